// Round 2
// baseline (1961.289 us; speedup 1.0000x reference)
//
#include <hip/hip_runtime.h>
#include <hip/hip_bf16.h>

#define NNODE 50000
#define M_PAD 50048
#define EDIM  256
#define HDIM  512
#define NEXP  5
#define GHID  128
#define NEDGE 800000
#define SLOTCAP 101504   // >= 2*NNODE + 10*127, 128-aligned
#define MAXT_ALL 792     // max (expert,rank) tiles total
#define MAXT_R   396     // max tiles per rank
#define HALFN 25000      // src-half split point for msg_sum L2 tiling
#define MSG_CHUNK 128    // dst nodes per msg_sum block
#define MSG_CHUNKS ((NNODE + MSG_CHUNK - 1) / MSG_CHUNK)   // 391

typedef __attribute__((ext_vector_type(8))) short  short8;
typedef __attribute__((ext_vector_type(4))) float  float4v;
typedef __attribute__((ext_vector_type(4))) unsigned short ushort4v;

typedef __attribute__((address_space(1))) const unsigned int gas_u32;
typedef __attribute__((address_space(3))) unsigned int       las_u32;

__device__ __forceinline__ void gl_lds16(const unsigned short* g, unsigned short* l) {
    __builtin_amdgcn_global_load_lds((gas_u32*)g, (las_u32*)l, 16, 0, 0);
}
__device__ __forceinline__ unsigned short f2b(float f) {
    unsigned u = __builtin_bit_cast(unsigned, f);
    u += 0x7FFFu + ((u >> 16) & 1u);
    return (unsigned short)(u >> 16);
}
__device__ __forceinline__ float b2f(unsigned short h) {
    unsigned u = ((unsigned)h) << 16;
    return __builtin_bit_cast(float, u);
}
__device__ __forceinline__ float fast_tanh(float y) {
    float ay = fabsf(y);
    float e  = __expf(-2.0f * ay);
    float t  = (1.0f - e) / (1.0f + e);
    return (y < 0.0f) ? -t : t;
}
__device__ __forceinline__ float gelu_tanh(float x) {
    float inner = 0.7978845608028654f * (x + 0.044715f * x * x * x);
    return 0.5f * x * (1.0f + fast_tanh(inner));
}

// ---------- weight transpose helpers (Bt layout: [out_col][k], bf16) ----------
__global__ void wtrans(const float* __restrict__ in, unsigned short* __restrict__ out,
                       int B, int R, int C) {
    int total = B * R * C;
    for (int i = blockIdx.x * blockDim.x + threadIdx.x; i < total; i += gridDim.x * blockDim.x) {
        int rc  = R * C;
        int b   = i / rc;
        int rem = i - b * rc;
        int c   = rem / R;
        int r   = rem - c * R;
        out[i] = f2b(in[(size_t)b * rc + (size_t)r * C + c]);
    }
}
// single matrix with output leading-dim + k-offset (for concatenated B)
__global__ void wtrans_k(const float* __restrict__ in, unsigned short* __restrict__ out,
                         int R, int C, int ldo, int ko) {
    int total = R * C;
    for (int i = blockIdx.x * blockDim.x + threadIdx.x; i < total; i += gridDim.x * blockDim.x) {
        int c = i / R;
        int r = i - c * R;
        out[(size_t)c * ldo + ko + r] = f2b(in[(size_t)r * C + c]);
    }
}
// hi/lo split transpose (for the fp32-fidelity gate GEMM)
__global__ void wtrans2(const float* __restrict__ in, unsigned short* __restrict__ oh,
                        unsigned short* __restrict__ ol, int R, int C) {
    int total = R * C;
    for (int i = blockIdx.x * blockDim.x + threadIdx.x; i < total; i += gridDim.x * blockDim.x) {
        int c = i / R;
        int r = i - c * R;
        float f = in[(size_t)r * C + c];
        unsigned short h = f2b(f);
        oh[i] = h;
        ol[i] = f2b(f - b2f(h));
    }
}

// ---------- gate layer 1, bf16x3 split MFMA: g = relu(concat(text,tab,str) @ Wg1 + bg1) ----------
__global__ __launch_bounds__(256) void gate128(
    const float* __restrict__ xtxt, const float* __restrict__ xtab, const float* __restrict__ xstr,
    const unsigned short* __restrict__ Bh, const unsigned short* __restrict__ Blo,
    const float* __restrict__ bg1, float* __restrict__ g) {
    __shared__ unsigned short Ash[128 * 64];
    __shared__ unsigned short Asl[128 * 64];
    __shared__ unsigned short Bsh[128 * 64];
    __shared__ unsigned short Bsl[128 * 64];
    const int t = threadIdx.x, w = t >> 6, lane = t & 63;
    const int ln = lane & 15, q = lane >> 4;
    const int wm = (w >> 1) * 64, wn = (w & 1) * 64;
    const int rb = w * 8 + (lane >> 3), kg = lane & 7;
    const int koff = (kg ^ (rb & 7)) * 8;
    const float* xs[3] = { xtxt, xtab, xstr };
    const unsigned short* Bgh = Bh  + (size_t)rb * 768 + koff;
    const unsigned short* Bgl = Blo + (size_t)rb * 768 + koff;
    unsigned short* Blh = &Bsh[rb * 64 + kg * 8];
    unsigned short* Bll = &Bsl[rb * 64 + kg * 8];
    float4v acc[4][4];
#pragma unroll
    for (int i = 0; i < 4; ++i)
#pragma unroll
        for (int j = 0; j < 4; ++j) acc[i][j] = (float4v){0.f, 0.f, 0.f, 0.f};

    for (int kt = 0; kt < 768; kt += 64) {
        const float* xp = xs[kt >> 8];
        const int kloc = kt & 255;
        __syncthreads();
#pragma unroll
        for (int it = 0; it < 4; ++it) {
            int row = blockIdx.y * 128 + rb + 32 * it;
            union { short8 v; unsigned short s[8]; } ph, pl;
            if (row < NNODE) {
                const float* sp = xp + (size_t)row * EDIM + kloc + koff;
                float4v a0 = *(const float4v*)sp;
                float4v a1 = *(const float4v*)(sp + 4);
#pragma unroll
                for (int c = 0; c < 4; ++c) {
                    unsigned short h0 = f2b(a0[c]);
                    ph.s[c] = h0; pl.s[c] = f2b(a0[c] - b2f(h0));
                    unsigned short h1 = f2b(a1[c]);
                    ph.s[4 + c] = h1; pl.s[4 + c] = f2b(a1[c] - b2f(h1));
                }
            } else {
#pragma unroll
                for (int c = 0; c < 8; ++c) { ph.s[c] = 0; pl.s[c] = 0; }
            }
            *(short8*)&Ash[(rb + 32 * it) * 64 + kg * 8] = ph.v;
            *(short8*)&Asl[(rb + 32 * it) * 64 + kg * 8] = pl.v;
            gl_lds16(Bgh + (size_t)it * 32 * 768 + kt, Blh + it * 32 * 64);
            gl_lds16(Bgl + (size_t)it * 32 * 768 + kt, Bll + it * 32 * 64);
        }
        __syncthreads();
#pragma unroll
        for (int kk = 0; kk < 2; ++kk) {
            short8 ah[4], al[4], bh[4], bl[4];
#pragma unroll
            for (int i = 0; i < 4; ++i) {
                int off = (wm + 16 * i + ln) * 64 + (((kk * 4 + q) ^ (ln & 7)) * 8);
                ah[i] = *(const short8*)&Ash[off];
                al[i] = *(const short8*)&Asl[off];
            }
#pragma unroll
            for (int j = 0; j < 4; ++j) {
                int off = (wn + 16 * j + ln) * 64 + (((kk * 4 + q) ^ (ln & 7)) * 8);
                bh[j] = *(const short8*)&Bsh[off];
                bl[j] = *(const short8*)&Bsl[off];
            }
#pragma unroll
            for (int i = 0; i < 4; ++i)
#pragma unroll
                for (int j = 0; j < 4; ++j) {
                    acc[i][j] = __builtin_amdgcn_mfma_f32_16x16x32_bf16(ah[i], bh[j], acc[i][j], 0, 0, 0);
                    acc[i][j] = __builtin_amdgcn_mfma_f32_16x16x32_bf16(ah[i], bl[j], acc[i][j], 0, 0, 0);
                    acc[i][j] = __builtin_amdgcn_mfma_f32_16x16x32_bf16(al[i], bh[j], acc[i][j], 0, 0, 0);
                }
        }
    }
    const int gm0 = blockIdx.y * 128 + wm;
#pragma unroll
    for (int i = 0; i < 4; ++i)
#pragma unroll
        for (int j = 0; j < 4; ++j) {
            int gn = wn + 16 * j + ln;
            float bc = bg1[gn];
#pragma unroll
            for (int r = 0; r < 4; ++r) {
                int gm = gm0 + 16 * i + q * 4 + r;
                g[(size_t)gm * GHID + gn] = fmaxf(acc[i][j][r] + bc, 0.f);
            }
        }
}

// ---------- gating: logits -> softmax -> top2 -> normalized gates (fp32) ----------
__global__ __launch_bounds__(256) void gating(
    const float* __restrict__ g, const float* __restrict__ Wg2, const float* __restrict__ bg2,
    float* __restrict__ gates, int* __restrict__ esel) {
    int wv = threadIdx.x >> 6, lane = threadIdx.x & 63;
    int n = blockIdx.x * 4 + wv;
    float p[NEXP];
    float g1 = g[(size_t)n * GHID + lane];
    float g2 = g[(size_t)n * GHID + 64 + lane];
#pragma unroll
    for (int e = 0; e < NEXP; ++e)
        p[e] = g1 * Wg2[lane * NEXP + e] + g2 * Wg2[(64 + lane) * NEXP + e];
#pragma unroll
    for (int off = 32; off > 0; off >>= 1)
#pragma unroll
        for (int e = 0; e < NEXP; ++e) p[e] += __shfl_xor(p[e], off, 64);
    if (lane == 0) {
        float l[NEXP], mx = -1e30f;
#pragma unroll
        for (int e = 0; e < NEXP; ++e) { l[e] = p[e] + bg2[e]; mx = fmaxf(mx, l[e]); }
        float pr[NEXP], s = 0.f;
#pragma unroll
        for (int e = 0; e < NEXP; ++e) { pr[e] = expf(l[e] - mx); s += pr[e]; }
#pragma unroll
        for (int e = 0; e < NEXP; ++e) pr[e] /= s;
        int i0 = 0;
#pragma unroll
        for (int e = 1; e < NEXP; ++e) if (pr[e] > pr[i0]) i0 = e;
        int i1 = -1;
#pragma unroll
        for (int e = 0; e < NEXP; ++e) if (e != i0 && (i1 < 0 || pr[e] > pr[i1])) i1 = e;
        float v0 = pr[i0], v1 = pr[i1], s2 = v0 + v1;
        gates[2 * n]     = v0 / s2;
        gates[2 * n + 1] = v1 / s2;
        esel[2 * n]      = i0;
        esel[2 * n + 1]  = i1;
    }
}

// ---------- slot machinery: per-(expert,rank) 128-padded compaction ----------
__global__ __launch_bounds__(256) void slot_count(const int* __restrict__ esel,
                                                  int* __restrict__ slotcnt) {
    __shared__ int h[10];
    if (threadIdx.x < 10) h[threadIdx.x] = 0;
    __syncthreads();
    int n = blockIdx.x * 256 + threadIdx.x;
    if (n < NNODE) {
        atomicAdd(&h[esel[2 * n] * 2 + 0], 1);
        atomicAdd(&h[esel[2 * n + 1] * 2 + 1], 1);
    }
    __syncthreads();
    if (threadIdx.x < 10) atomicAdd(&slotcnt[threadIdx.x], h[threadIdx.x]);
}
// header: [0]=tiles_all, [1]=tiles_rank0, [2]=tiles_rank1
__global__ void seg_plan(const int* __restrict__ slotcnt, int* __restrict__ cursor,
                         int* __restrict__ header, int2* __restrict__ meta_all,
                         int2* __restrict__ meta_r0, int2* __restrict__ meta_r1) {
    if (threadIdx.x == 0 && blockIdx.x == 0) {
        int base = 0, ta = 0, t0 = 0, t1 = 0;
        for (int s = 0; s < 10; ++s) {
            cursor[s] = base;
            int nt = (slotcnt[s] + 127) >> 7;
            for (int k = 0; k < nt; ++k) {
                int2 m; m.x = s; m.y = base + k * 128;
                meta_all[ta++] = m;
                if (s & 1) meta_r1[t1++] = m; else meta_r0[t0++] = m;
            }
            base += nt * 128;
        }
        header[0] = ta; header[1] = t0; header[2] = t1;
    }
}
__global__ __launch_bounds__(256) void slot_fill(
    const int* __restrict__ esel, const float* __restrict__ gates, int* __restrict__ cursor,
    int* __restrict__ rowlist, float* __restrict__ gateval) {
    __shared__ int h[10], base[10];
    if (threadIdx.x < 10) h[threadIdx.x] = 0;
    __syncthreads();
    int n = blockIdx.x * 256 + threadIdx.x;
    int s0 = 0, s1 = 0, p0 = 0, p1 = 0;
    bool on = (n < NNODE);
    if (on) {
        s0 = esel[2 * n] * 2;
        s1 = esel[2 * n + 1] * 2 + 1;
        p0 = atomicAdd(&h[s0], 1);
        p1 = atomicAdd(&h[s1], 1);
    }
    __syncthreads();
    if (threadIdx.x < 10) base[threadIdx.x] = atomicAdd(&cursor[threadIdx.x], h[threadIdx.x]);
    __syncthreads();
    if (on) {
        int q0 = base[s0] + p0, q1 = base[s1] + p1;
        rowlist[q0] = n; gateval[q0] = gates[2 * n];
        rowlist[q1] = n; gateval[q1] = gates[2 * n + 1];
    }
}

// ---------- expert layer 1 (compacted): h1[slot] = gelu(x[rowlist[slot]] @ We1[e] + be1[e]) ----------
__global__ __launch_bounds__(256) void gemm_moe1(
    const float* __restrict__ xtab, const float* __restrict__ xstr, const float* __restrict__ xtxt,
    const unsigned short* __restrict__ We1t, const float* __restrict__ be1,
    const int* __restrict__ header, const int2* __restrict__ meta,
    const int* __restrict__ rowlist, unsigned short* __restrict__ h1) {
    if ((int)blockIdx.y >= header[0]) return;
    __shared__ unsigned short As[128 * 64];
    __shared__ unsigned short Bs[128 * 64];
    int2 mt = meta[blockIdx.y];
    const int eid = mt.x >> 1, rowbase = mt.y;
    const float* xf = (eid == 0) ? xtab : ((eid == 1 || eid == 4) ? xstr : xtxt);
    const int t = threadIdx.x, w = t >> 6, lane = t & 63;
    const int ln = lane & 15, q = lane >> 4;
    const int wm = (w >> 1) * 64, wn = (w & 1) * 64;
    const int rb = w * 8 + (lane >> 3), kg = lane & 7;
    const int koff = (kg ^ (rb & 7)) * 8;
    int rows[4];
#pragma unroll
    for (int it = 0; it < 4; ++it) {
        int rr = rowlist[rowbase + rb + 32 * it];
        rows[it] = (rr < 0) ? 0 : rr;
    }
    const unsigned short* Bg = We1t + (size_t)eid * HDIM * EDIM
                             + (size_t)(blockIdx.x * 128 + rb) * EDIM + koff;
    unsigned short* Bl = &Bs[rb * 64 + kg * 8];
    float4v acc[4][4];
#pragma unroll
    for (int i = 0; i < 4; ++i)
#pragma unroll
        for (int j = 0; j < 4; ++j) acc[i][j] = (float4v){0.f, 0.f, 0.f, 0.f};

    for (int kt = 0; kt < EDIM; kt += 64) {
        __syncthreads();
#pragma unroll
        for (int it = 0; it < 4; ++it) {
            const float* sp = xf + (size_t)rows[it] * EDIM + kt + koff;
            float4v a0 = *(const float4v*)sp;
            float4v a1 = *(const float4v*)(sp + 4);
            union { short8 v; unsigned short s[8]; } pk;
#pragma unroll
            for (int c = 0; c < 4; ++c) { pk.s[c] = f2b(a0[c]); pk.s[4 + c] = f2b(a1[c]); }
            *(short8*)&As[(rb + 32 * it) * 64 + kg * 8] = pk.v;
            gl_lds16(Bg + (size_t)it * 32 * EDIM + kt, Bl + it * 32 * 64);
        }
        __syncthreads();
#pragma unroll
        for (int kk = 0; kk < 2; ++kk) {
            short8 af[4], bf[4];
#pragma unroll
            for (int i = 0; i < 4; ++i)
                af[i] = *(const short8*)&As[(wm + 16 * i + ln) * 64 + (((kk * 4 + q) ^ (ln & 7)) * 8)];
#pragma unroll
            for (int j = 0; j < 4; ++j)
                bf[j] = *(const short8*)&Bs[(wn + 16 * j + ln) * 64 + (((kk * 4 + q) ^ (ln & 7)) * 8)];
#pragma unroll
            for (int i = 0; i < 4; ++i)
#pragma unroll
                for (int j = 0; j < 4; ++j)
                    acc[i][j] = __builtin_amdgcn_mfma_f32_16x16x32_bf16(af[i], bf[j], acc[i][j], 0, 0, 0);
        }
    }
    const int gn0 = blockIdx.x * 128 + wn;
#pragma unroll
    for (int i = 0; i < 4; ++i)
#pragma unroll
        for (int j = 0; j < 4; ++j) {
            int gn = gn0 + 16 * j + ln;
            float bc = be1[eid * HDIM + gn];
#pragma unroll
            for (int r = 0; r < 4; ++r) {
                int slot = rowbase + wm + 16 * i + q * 4 + r;
                h1[(size_t)slot * HDIM + gn] = f2b(gelu_tanh(acc[i][j][r] + bc));
            }
        }
}

// ---------- expert layer 2 (compacted, scatter): nf[node] (+)= gate*(h1[slot]@We2[e] + be2[e]) ----------
template<int RMW>
__global__ __launch_bounds__(256) void gemm_moe2(
    const unsigned short* __restrict__ h1, const unsigned short* __restrict__ We2t,
    const float* __restrict__ be2, const int* __restrict__ header,
    const int2* __restrict__ meta, const int* __restrict__ rowlist,
    const float* __restrict__ gateval, unsigned short* __restrict__ nf) {
    if ((int)blockIdx.y >= header[RMW ? 2 : 1]) return;
    __shared__ unsigned short As[128 * 64];
    __shared__ unsigned short Bs[128 * 64];
    int2 mt = meta[blockIdx.y];
    const int eid = mt.x >> 1, rowbase = mt.y;
    const int t = threadIdx.x, w = t >> 6, lane = t & 63;
    const int ln = lane & 15, q = lane >> 4;
    const int wm = (w >> 1) * 64, wn = (w & 1) * 64;
    const int rb = w * 8 + (lane >> 3), kg = lane & 7;
    const int koff = (kg ^ (rb & 7)) * 8;
    const unsigned short* Ag = h1 + (size_t)(rowbase + rb) * HDIM + koff;
    const unsigned short* Bg = We2t + (size_t)eid * HDIM * HDIM
                             + (size_t)(blockIdx.x * 128 + rb) * HDIM + koff;
    unsigned short* Al = &As[rb * 64 + kg * 8];
    unsigned short* Bl = &Bs[rb * 64 + kg * 8];
    float4v acc[4][4];
#pragma unroll
    for (int i = 0; i < 4; ++i)
#pragma unroll
        for (int j = 0; j < 4; ++j) acc[i][j] = (float4v){0.f, 0.f, 0.f, 0.f};

    for (int kt = 0; kt < HDIM; kt += 64) {
        __syncthreads();
#pragma unroll
        for (int it = 0; it < 4; ++it) {
            gl_lds16(Ag + (size_t)it * 32 * HDIM + kt, Al + it * 32 * 64);
            gl_lds16(Bg + (size_t)it * 32 * HDIM + kt, Bl + it * 32 * 64);
        }
        __syncthreads();
#pragma unroll
        for (int kk = 0; kk < 2; ++kk) {
            short8 af[4], bf[4];
#pragma unroll
            for (int i = 0; i < 4; ++i)
                af[i] = *(const short8*)&As[(wm + 16 * i + ln) * 64 + (((kk * 4 + q) ^ (ln & 7)) * 8)];
#pragma unroll
            for (int j = 0; j < 4; ++j)
                bf[j] = *(const short8*)&Bs[(wn + 16 * j + ln) * 64 + (((kk * 4 + q) ^ (ln & 7)) * 8)];
#pragma unroll
            for (int i = 0; i < 4; ++i)
#pragma unroll
                for (int j = 0; j < 4; ++j)
                    acc[i][j] = __builtin_amdgcn_mfma_f32_16x16x32_bf16(af[i], bf[j], acc[i][j], 0, 0, 0);
        }
    }
    const int gn0 = blockIdx.x * 128 + wn;
#pragma unroll
    for (int i = 0; i < 4; ++i)
#pragma unroll
        for (int r = 0; r < 4; ++r) {
            int slot = rowbase + wm + 16 * i + q * 4 + r;
            int node = rowlist[slot];
            if (node >= 0) {
                float gt = gateval[slot];
#pragma unroll
                for (int j = 0; j < 4; ++j) {
                    int gn = gn0 + 16 * j + ln;
                    size_t o = (size_t)node * HDIM + gn;
                    float v = gt * (acc[i][j][r] + be2[eid * HDIM + gn]);
                    nf[o] = RMW ? f2b(b2f(nf[o]) + v) : f2b(v);
                }
            }
        }
}

// ---------- GNN fused layer: C = relu([h, agg] @ [Wself; Wnbr])  (K=1024 concat) ----------
template<int FINAL>
__global__ __launch_bounds__(256) void gemm_gnn(
    const unsigned short* __restrict__ A0, const unsigned short* __restrict__ A1,
    const unsigned short* __restrict__ Bt, unsigned short* __restrict__ Cb,
    float* __restrict__ Cf) {
    __shared__ unsigned short As[128 * 64];
    __shared__ unsigned short Bs[128 * 64];
    const int t = threadIdx.x, w = t >> 6, lane = t & 63;
    const int ln = lane & 15, q = lane >> 4;
    const int wm = (w >> 1) * 64, wn = (w & 1) * 64;
    const int rb = w * 8 + (lane >> 3), kg = lane & 7;
    const int koff = (kg ^ (rb & 7)) * 8;
    const unsigned short* Ag0 = A0 + (size_t)(blockIdx.y * 128 + rb) * HDIM + koff;
    const unsigned short* Ag1 = A1 + (size_t)(blockIdx.y * 128 + rb) * HDIM + koff;
    const unsigned short* Bg  = Bt + (size_t)(blockIdx.x * 128 + rb) * 1024 + koff;
    unsigned short* Al = &As[rb * 64 + kg * 8];
    unsigned short* Bl = &Bs[rb * 64 + kg * 8];
    float4v acc[4][4];
#pragma unroll
    for (int i = 0; i < 4; ++i)
#pragma unroll
        for (int j = 0; j < 4; ++j) acc[i][j] = (float4v){0.f, 0.f, 0.f, 0.f};

    for (int kt = 0; kt < 1024; kt += 64) {
        __syncthreads();
#pragma unroll
        for (int it = 0; it < 4; ++it) {
            const unsigned short* asrc = (kt < HDIM)
                ? (Ag0 + (size_t)it * 32 * HDIM + kt)
                : (Ag1 + (size_t)it * 32 * HDIM + (kt - HDIM));
            gl_lds16(asrc, Al + it * 32 * 64);
            gl_lds16(Bg + (size_t)it * 32 * 1024 + kt, Bl + it * 32 * 64);
        }
        __syncthreads();
#pragma unroll
        for (int kk = 0; kk < 2; ++kk) {
            short8 af[4], bf[4];
#pragma unroll
            for (int i = 0; i < 4; ++i)
                af[i] = *(const short8*)&As[(wm + 16 * i + ln) * 64 + (((kk * 4 + q) ^ (ln & 7)) * 8)];
#pragma unroll
            for (int j = 0; j < 4; ++j)
                bf[j] = *(const short8*)&Bs[(wn + 16 * j + ln) * 64 + (((kk * 4 + q) ^ (ln & 7)) * 8)];
#pragma unroll
            for (int i = 0; i < 4; ++i)
#pragma unroll
                for (int j = 0; j < 4; ++j)
                    acc[i][j] = __builtin_amdgcn_mfma_f32_16x16x32_bf16(af[i], bf[j], acc[i][j], 0, 0, 0);
        }
    }
    const int gm0 = blockIdx.y * 128 + wm;
    const int gn0 = blockIdx.x * 128 + wn;
#pragma unroll
    for (int i = 0; i < 4; ++i)
#pragma unroll
        for (int j = 0; j < 4; ++j) {
            int gn = gn0 + 16 * j + ln;
#pragma unroll
            for (int r = 0; r < 4; ++r) {
                int gm = gm0 + 16 * i + q * 4 + r;
                float v = fmaxf(acc[i][j][r], 0.f);
                if (FINAL) {
                    if (gm < NNODE) Cf[(size_t)gm * HDIM + gn] = v;
                } else {
                    Cb[(size_t)gm * HDIM + gn] = f2b(v);
                }
            }
        }
}

// ---------- CSR build, (dst, src-half) bucketed: segments ordered [n][half] ----------
__global__ void hist2(const int* __restrict__ src, const int* __restrict__ dst,
                      int* __restrict__ deg2) {
    int i = blockIdx.x * blockDim.x + threadIdx.x;
    if (i < NEDGE) atomicAdd(&deg2[2 * dst[i] + (src[i] >= HALFN)], 1);
}
__global__ void scan_block(const int* __restrict__ in, int* __restrict__ incl,
                           int* __restrict__ bsum, int n) {
    __shared__ int s[256];
    int i = blockIdx.x * 256 + threadIdx.x;
    s[threadIdx.x] = (i < n) ? in[i] : 0;
    __syncthreads();
    for (int off = 1; off < 256; off <<= 1) {
        int t = (threadIdx.x >= (unsigned)off) ? s[threadIdx.x - off] : 0;
        __syncthreads();
        s[threadIdx.x] += t;
        __syncthreads();
    }
    if (i < n) incl[i] = s[threadIdx.x];
    if (bsum != nullptr && threadIdx.x == 255) bsum[blockIdx.x] = s[255];
}
// single-block scan for up to 1024 block sums
__global__ void scan_lvl2(const int* __restrict__ in, int* __restrict__ out, int n) {
    __shared__ int s[1024];
    int i = threadIdx.x;
    s[i] = (i < n) ? in[i] : 0;
    __syncthreads();
    for (int off = 1; off < 1024; off <<= 1) {
        int t = (i >= (unsigned)off) ? s[i - off] : 0;
        __syncthreads();
        s[i] += t;
        __syncthreads();
    }
    if (i < n) out[i] = s[i];
}
__global__ void scan_fix2(const int* __restrict__ incl, const int* __restrict__ deg2,
                          const int* __restrict__ bscan, int* __restrict__ rowstart2,
                          int* __restrict__ ecur2, int n) {
    int i = blockIdx.x * blockDim.x + threadIdx.x;
    if (i < n) {
        int b = i >> 8;
        int add = (b > 0) ? bscan[b - 1] : 0;
        int st = incl[i] - deg2[i] + add;
        rowstart2[i] = st;
        ecur2[i] = st;
    }
}
__global__ void fill_csr2(const int* __restrict__ src, const int* __restrict__ dst,
                          int* __restrict__ ecur2, int* __restrict__ srcs) {
    int e = blockIdx.x * blockDim.x + threadIdx.x;
    if (e < NEDGE) {
        int s = src[e];
        int pos = atomicAdd(&ecur2[2 * dst[e] + (s >= HALFN)], 1);
        srcs[pos] = s;
    }
}

// ---------- XCD-L2-resident sliced segment-sum: agg[n] = sum_{s in nbrs(n)} h[s] ----------
// Each 1KB h-row is split into 8 slices of 128B; slice s is processed ONLY by blocks
// with blockIdx%8==s, which the round-robin dispatch places on XCD s. Per-XCD gather
// footprint: 50000 rows x 128B = 6.4MB; the src-half phases (all dst for src<HALFN
// first, fp32 partials held in LDS, then src>=HALFN) cut the instantaneous footprint
// to ~3.2MB, inside the 4MB per-XCD L2 -> gathers become L2 hits instead of fabric
// traffic. Output stores are nontemporal to avoid polluting the resident slice.
__global__ __launch_bounds__(256) void msg_sum_s(
    const unsigned short* __restrict__ h, const int* __restrict__ rowstart2,
    const int* __restrict__ deg2, const int* __restrict__ srcs,
    unsigned short* __restrict__ agg) {
    __shared__ float part[4][32][64];   // [wave][dst_local][lane] fp32 partials, 32KB
    const int wv = threadIdx.x >> 6, lane = threadIdx.x & 63;
    const int slice = blockIdx.x & 7;          // == XCD id under round-robin dispatch
    const int chunk = blockIdx.x >> 3;
    const int nbase = chunk * MSG_CHUNK + wv * 32;
    const unsigned short* hp = h + (size_t)slice * 64 + lane;
#pragma unroll 1
    for (int ph = 0; ph < 2; ++ph) {
#pragma unroll 1
        for (int k = 0; k < 32; ++k) {
            int n = nbase + k;
            if (n >= NNODE) break;
            int st = rowstart2[2 * n + ph];
            int d  = deg2[2 * n + ph];
            float a = (ph == 0) ? 0.f : part[wv][k][lane];
            int t = 0;
            for (; t + 8 <= d; t += 8) {
                int s0 = srcs[st + t],     s1 = srcs[st + t + 1];
                int s2 = srcs[st + t + 2], s3 = srcs[st + t + 3];
                int s4 = srcs[st + t + 4], s5 = srcs[st + t + 5];
                int s6 = srcs[st + t + 6], s7 = srcs[st + t + 7];
                unsigned short v0 = hp[(size_t)s0 * HDIM], v1 = hp[(size_t)s1 * HDIM];
                unsigned short v2 = hp[(size_t)s2 * HDIM], v3 = hp[(size_t)s3 * HDIM];
                unsigned short v4 = hp[(size_t)s4 * HDIM], v5 = hp[(size_t)s5 * HDIM];
                unsigned short v6 = hp[(size_t)s6 * HDIM], v7 = hp[(size_t)s7 * HDIM];
                a += ((b2f(v0) + b2f(v1)) + (b2f(v2) + b2f(v3)))
                   + ((b2f(v4) + b2f(v5)) + (b2f(v6) + b2f(v7)));
            }
            for (; t < d; ++t) {
                int s = srcs[st + t];
                a += b2f(hp[(size_t)s * HDIM]);
            }
            if (ph == 0) {
                part[wv][k][lane] = a;
            } else {
                __builtin_nontemporal_store(
                    f2b(a), agg + (size_t)n * HDIM + slice * 64 + lane);
            }
        }
    }
}

extern "C" void kernel_launch(void* const* d_in, const int* in_sizes, int n_in,
                              void* d_out, int out_size, void* d_ws, size_t ws_size,
                              hipStream_t stream) {
    (void)in_sizes; (void)n_in; (void)out_size; (void)ws_size;
    const float* text       = (const float*)d_in[0];
    const float* tabular    = (const float*)d_in[1];
    const float* structured = (const float*)d_in[2];
    const int*   e_in       = (const int*)d_in[3];
    const float* Wg1  = (const float*)d_in[4];
    const float* bg1  = (const float*)d_in[5];
    const float* Wg2  = (const float*)d_in[6];
    const float* bg2  = (const float*)d_in[7];
    const float* We1  = (const float*)d_in[8];
    const float* be1  = (const float*)d_in[9];
    const float* We2  = (const float*)d_in[10];
    const float* be2  = (const float*)d_in[11];
    const float* Wself = (const float*)d_in[12];
    const float* Wnbr  = (const float*)d_in[13];
    const int* src = e_in;
    const int* dst = e_in + NEDGE;
    float* dout = (float*)d_out;

    // ---- workspace carve-up (regions overlap across phases; ~220 MB total) ----
    char* w = (char*)d_ws;
    auto alloc = [&](size_t bytes) { char* p = w; w += (bytes + 511) & ~(size_t)511; return p; };
    const size_t SZ_H = (size_t)M_PAD * HDIM * 2;            // 51.25 MB
    unsigned short* We1t  = (unsigned short*)alloc((size_t)NEXP * HDIM * EDIM * 2);
    unsigned short* We2t  = (unsigned short*)alloc((size_t)NEXP * HDIM * HDIM * 2);
    unsigned short* Wcat0 = (unsigned short*)alloc((size_t)HDIM * 1024 * 2);
    unsigned short* Wcat1 = (unsigned short*)alloc((size_t)HDIM * 1024 * 2);
    unsigned short* Wg1h  = (unsigned short*)alloc((size_t)GHID * 768 * 2);
    unsigned short* Wg1l  = (unsigned short*)alloc((size_t)GHID * 768 * 2);
    float* gates    = (float*)alloc((size_t)NNODE * 2 * 4);
    int*   esel     = (int*)alloc((size_t)NNODE * 2 * 4);
    int*   slotcnt  = (int*)alloc(16 * 4);
    int*   scursor  = (int*)alloc(16 * 4);
    int*   header   = (int*)alloc(16 * 4);
    int2*  meta_all = (int2*)alloc((size_t)MAXT_ALL * 8);
    int2*  meta_r0  = (int2*)alloc((size_t)MAXT_R * 8);
    int2*  meta_r1  = (int2*)alloc((size_t)MAXT_R * 8);
    int*   rowlist  = (int*)alloc((size_t)SLOTCAP * 4);
    float* gateval  = (float*)alloc((size_t)SLOTCAP * 4);
    int*   deg2     = (int*)alloc((size_t)2 * NNODE * 4);
    int*   incl     = (int*)alloc((size_t)2 * NNODE * 4);
    int*   bsum     = (int*)alloc(1024 * 4);
    int*   bscan    = (int*)alloc(1024 * 4);
    int*   rowstart2= (int*)alloc((size_t)2 * NNODE * 4);
    int*   ecur2    = (int*)alloc((size_t)2 * NNODE * 4);
    int*   srcs     = (int*)alloc((size_t)NEDGE * 4);
    unsigned short* nfb = (unsigned short*)alloc(SZ_H);
    // region A: gbuf (gate hidden, fp32) dead after gating; aggb alive only in GNN
    char* regA = alloc((size_t)M_PAD * GHID * 4 > SZ_H ? (size_t)M_PAD * GHID * 4 : SZ_H);
    float*          gbuf = (float*)regA;
    unsigned short* aggb = (unsigned short*)regA;
    // region B: h1c (compacted expert hidden) dead after moe2; hb alive only in GNN
    char* regB = alloc((size_t)SLOTCAP * HDIM * 2);
    unsigned short* h1c = (unsigned short*)regB;
    unsigned short* hb  = (unsigned short*)regB;

    // ---- weight prep ----
    wtrans  <<<512, 256, 0, stream>>>(We1, We1t, NEXP, EDIM, HDIM);
    wtrans  <<<512, 256, 0, stream>>>(We2, We2t, NEXP, HDIM, HDIM);
    wtrans_k<<<512, 256, 0, stream>>>(Wself,               Wcat0, HDIM, HDIM, 1024, 0);
    wtrans_k<<<512, 256, 0, stream>>>(Wnbr,                Wcat0, HDIM, HDIM, 1024, 512);
    wtrans_k<<<512, 256, 0, stream>>>(Wself + HDIM * HDIM, Wcat1, HDIM, HDIM, 1024, 0);
    wtrans_k<<<512, 256, 0, stream>>>(Wnbr  + HDIM * HDIM, Wcat1, HDIM, HDIM, 1024, 512);
    wtrans2 <<<512, 256, 0, stream>>>(Wg1, Wg1h, Wg1l, 3 * EDIM, GHID);

    hipMemsetAsync(slotcnt, 0, 16 * 4, stream);
    hipMemsetAsync(rowlist, 0xFF, (size_t)SLOTCAP * 4, stream);
    hipMemsetAsync(deg2, 0, (size_t)2 * NNODE * 4, stream);

    // ---- gate (bf16x3 split, fp32 fidelity) + routing ----
    gate128<<<dim3(1, M_PAD / 128), 256, 0, stream>>>(text, tabular, structured,
                                                      Wg1h, Wg1l, bg1, gbuf);
    gating<<<NNODE / 4, 256, 0, stream>>>(gbuf, Wg2, bg2, gates, esel);

    // ---- compaction plan ----
    slot_count<<<(NNODE + 255) / 256, 256, 0, stream>>>(esel, slotcnt);
    seg_plan<<<1, 64, 0, stream>>>(slotcnt, scursor, header, meta_all, meta_r0, meta_r1);
    slot_fill<<<(NNODE + 255) / 256, 256, 0, stream>>>(esel, gates, scursor, rowlist, gateval);

    // ---- experts on routed rows only ----
    gemm_moe1<<<dim3(HDIM / 128, MAXT_ALL), 256, 0, stream>>>(
        tabular, structured, text, We1t, be1, header, meta_all, rowlist, h1c);
    gemm_moe2<0><<<dim3(HDIM / 128, MAXT_R), 256, 0, stream>>>(
        h1c, We2t, be2, header, meta_r0, rowlist, gateval, nfb);
    gemm_moe2<1><<<dim3(HDIM / 128, MAXT_R), 256, 0, stream>>>(
        h1c, We2t, be2, header, meta_r1, rowlist, gateval, nfb);

    // ---- CSR of edges grouped by (dst, src-half) ----
    const int N2  = 2 * NNODE;
    const int NB2 = (N2 + 255) / 256;   // 391
    hist2<<<(NEDGE + 255) / 256, 256, 0, stream>>>(src, dst, deg2);
    scan_block<<<NB2, 256, 0, stream>>>(deg2, incl, bsum, N2);
    scan_lvl2<<<1, 1024, 0, stream>>>(bsum, bscan, NB2);
    scan_fix2<<<NB2, 256, 0, stream>>>(incl, deg2, bscan, rowstart2, ecur2, N2);
    fill_csr2<<<(NEDGE + 255) / 256, 256, 0, stream>>>(src, dst, ecur2, srcs);

    // ---- GNN layer 0: agg = segsum(nf); h = relu([nf,agg] @ Wcat0) ----
    msg_sum_s<<<8 * MSG_CHUNKS, 256, 0, stream>>>(nfb, rowstart2, deg2, srcs, aggb);
    gemm_gnn<0><<<dim3(HDIM / 128, M_PAD / 128), 256, 0, stream>>>(nfb, aggb, Wcat0, hb, nullptr);

    // ---- GNN layer 1: agg = segsum(h); out = relu([h,agg] @ Wcat1) ----
    msg_sum_s<<<8 * MSG_CHUNKS, 256, 0, stream>>>(hb, rowstart2, deg2, srcs, aggb);
    gemm_gnn<1><<<dim3(HDIM / 128, M_PAD / 128), 256, 0, stream>>>(hb, aggb, Wcat1, nullptr, dout);
}

// Round 3
// 1101.077 us; speedup vs baseline: 1.7812x; 1.7812x over previous
//
#include <hip/hip_runtime.h>
#include <hip/hip_bf16.h>

#define NNODE 50000
#define M_PAD 50048
#define EDIM  256
#define HDIM  512
#define NEXP  5
#define GHID  128
#define NEDGE 800000
#define SLOTCAP 101504   // >= 2*NNODE + 10*127, 128-aligned
#define MAXT_ALL 792     // max (expert,rank) tiles total
#define MAXT_R   396     // max tiles per rank

typedef __attribute__((ext_vector_type(8))) short  short8;
typedef __attribute__((ext_vector_type(4))) float  float4v;
typedef __attribute__((ext_vector_type(4))) unsigned short ushort4v;

typedef __attribute__((address_space(1))) const unsigned int gas_u32;
typedef __attribute__((address_space(3))) unsigned int       las_u32;

__device__ __forceinline__ void gl_lds16(const unsigned short* g, unsigned short* l) {
    __builtin_amdgcn_global_load_lds((gas_u32*)g, (las_u32*)l, 16, 0, 0);
}
__device__ __forceinline__ unsigned short f2b(float f) {
    unsigned u = __builtin_bit_cast(unsigned, f);
    u += 0x7FFFu + ((u >> 16) & 1u);
    return (unsigned short)(u >> 16);
}
__device__ __forceinline__ float b2f(unsigned short h) {
    unsigned u = ((unsigned)h) << 16;
    return __builtin_bit_cast(float, u);
}
__device__ __forceinline__ float fast_tanh(float y) {
    float ay = fabsf(y);
    float e  = __expf(-2.0f * ay);
    float t  = (1.0f - e) / (1.0f + e);
    return (y < 0.0f) ? -t : t;
}
__device__ __forceinline__ float gelu_tanh(float x) {
    float inner = 0.7978845608028654f * (x + 0.044715f * x * x * x);
    return 0.5f * x * (1.0f + fast_tanh(inner));
}

// ---------- unified weight prep: one kernel replaces 7 transpose launches ----------
// Segment map (compile-time, element index i over 3,112,960):
//  [0, 655360)           We1t  [5][512c][256r]   <- We1[5][256r][512c]
//  [655360, 1966080)     We2t  [5][512c][512r]   <- We2[5][512r][512c]
//  [1966080, 3014656)    Wcat0/Wcat1 quarters    <- Wself[2]/Wnbr[2] (ld 1024, ko 0/512)
//  [3014656, 3112960)    Wg1h/Wg1l hi/lo split   <- Wg1[768r][128c]
#define WP_N0 655360
#define WP_C1 1966080
#define WP_C2 3014656
#define WP_TOT 3112960
__global__ __launch_bounds__(256) void wprep(
    const float* __restrict__ We1, const float* __restrict__ We2,
    const float* __restrict__ Wself, const float* __restrict__ Wnbr,
    const float* __restrict__ Wg1,
    unsigned short* __restrict__ We1t, unsigned short* __restrict__ We2t,
    unsigned short* __restrict__ Wcat0, unsigned short* __restrict__ Wcat1,
    unsigned short* __restrict__ Wg1h, unsigned short* __restrict__ Wg1l) {
    for (int i = blockIdx.x * blockDim.x + threadIdx.x; i < WP_TOT;
         i += gridDim.x * blockDim.x) {
        if (i < WP_N0) {                      // We1t: B=5, R=256, C=512
            int b = i >> 17, rem = i & 131071;
            int c = rem >> 8, r = rem & 255;
            We1t[i] = f2b(We1[(size_t)b * 131072 + (size_t)r * 512 + c]);
        } else if (i < WP_C1) {               // We2t: B=5, R=512, C=512
            int j = i - WP_N0;
            int b = j >> 18, rem = j & 262143;
            int c = rem >> 9, r = rem & 511;
            We2t[j] = f2b(We2[(size_t)b * 262144 + (size_t)r * 512 + c]);
        } else if (i < WP_C2) {               // Wcat quarters: R=C=512, ldo=1024
            int j = i - WP_C1;
            int qd = j >> 18, k = j & 262143;
            int c = k >> 9, r = k & 511;
            const float* in = (qd & 1) ? Wnbr : Wself;
            if (qd >> 1) in += 262144;        // layer 1
            unsigned short* out = (qd >> 1) ? Wcat1 : Wcat0;
            int ko = (qd & 1) * 512;
            out[(size_t)c * 1024 + ko + r] = f2b(in[(size_t)r * 512 + c]);
        } else {                              // Wg1 hi/lo: R=768, C=128
            int j = i - WP_C2;
            int c = j / 768, r = j - c * 768;
            float f = Wg1[(size_t)r * 128 + c];
            unsigned short hi = f2b(f);
            Wg1h[j] = hi;
            Wg1l[j] = f2b(f - b2f(hi));
        }
    }
}

// ---------- gate layer 1, bf16x3 split MFMA: g = relu(concat(text,tab,str) @ Wg1 + bg1) ----------
__global__ __launch_bounds__(256) void gate128(
    const float* __restrict__ xtxt, const float* __restrict__ xtab, const float* __restrict__ xstr,
    const unsigned short* __restrict__ Bh, const unsigned short* __restrict__ Blo,
    const float* __restrict__ bg1, float* __restrict__ g) {
    __shared__ unsigned short Ash[128 * 64];
    __shared__ unsigned short Asl[128 * 64];
    __shared__ unsigned short Bsh[128 * 64];
    __shared__ unsigned short Bsl[128 * 64];
    const int t = threadIdx.x, w = t >> 6, lane = t & 63;
    const int ln = lane & 15, q = lane >> 4;
    const int wm = (w >> 1) * 64, wn = (w & 1) * 64;
    const int rb = w * 8 + (lane >> 3), kg = lane & 7;
    const int koff = (kg ^ (rb & 7)) * 8;
    const float* xs[3] = { xtxt, xtab, xstr };
    const unsigned short* Bgh = Bh  + (size_t)rb * 768 + koff;
    const unsigned short* Bgl = Blo + (size_t)rb * 768 + koff;
    unsigned short* Blh = &Bsh[rb * 64 + kg * 8];
    unsigned short* Bll = &Bsl[rb * 64 + kg * 8];
    float4v acc[4][4];
#pragma unroll
    for (int i = 0; i < 4; ++i)
#pragma unroll
        for (int j = 0; j < 4; ++j) acc[i][j] = (float4v){0.f, 0.f, 0.f, 0.f};

    for (int kt = 0; kt < 768; kt += 64) {
        const float* xp = xs[kt >> 8];
        const int kloc = kt & 255;
        __syncthreads();
#pragma unroll
        for (int it = 0; it < 4; ++it) {
            int row = blockIdx.y * 128 + rb + 32 * it;
            union { short8 v; unsigned short s[8]; } ph, pl;
            if (row < NNODE) {
                const float* sp = xp + (size_t)row * EDIM + kloc + koff;
                float4v a0 = *(const float4v*)sp;
                float4v a1 = *(const float4v*)(sp + 4);
#pragma unroll
                for (int c = 0; c < 4; ++c) {
                    unsigned short h0 = f2b(a0[c]);
                    ph.s[c] = h0; pl.s[c] = f2b(a0[c] - b2f(h0));
                    unsigned short h1 = f2b(a1[c]);
                    ph.s[4 + c] = h1; pl.s[4 + c] = f2b(a1[c] - b2f(h1));
                }
            } else {
#pragma unroll
                for (int c = 0; c < 8; ++c) { ph.s[c] = 0; pl.s[c] = 0; }
            }
            *(short8*)&Ash[(rb + 32 * it) * 64 + kg * 8] = ph.v;
            *(short8*)&Asl[(rb + 32 * it) * 64 + kg * 8] = pl.v;
            gl_lds16(Bgh + (size_t)it * 32 * 768 + kt, Blh + it * 32 * 64);
            gl_lds16(Bgl + (size_t)it * 32 * 768 + kt, Bll + it * 32 * 64);
        }
        __syncthreads();
#pragma unroll
        for (int kk = 0; kk < 2; ++kk) {
            short8 ah[4], al[4], bh[4], bl[4];
#pragma unroll
            for (int i = 0; i < 4; ++i) {
                int off = (wm + 16 * i + ln) * 64 + (((kk * 4 + q) ^ (ln & 7)) * 8);
                ah[i] = *(const short8*)&Ash[off];
                al[i] = *(const short8*)&Asl[off];
            }
#pragma unroll
            for (int j = 0; j < 4; ++j) {
                int off = (wn + 16 * j + ln) * 64 + (((kk * 4 + q) ^ (ln & 7)) * 8);
                bh[j] = *(const short8*)&Bsh[off];
                bl[j] = *(const short8*)&Bsl[off];
            }
#pragma unroll
            for (int i = 0; i < 4; ++i)
#pragma unroll
                for (int j = 0; j < 4; ++j) {
                    acc[i][j] = __builtin_amdgcn_mfma_f32_16x16x32_bf16(ah[i], bh[j], acc[i][j], 0, 0, 0);
                    acc[i][j] = __builtin_amdgcn_mfma_f32_16x16x32_bf16(ah[i], bl[j], acc[i][j], 0, 0, 0);
                    acc[i][j] = __builtin_amdgcn_mfma_f32_16x16x32_bf16(al[i], bh[j], acc[i][j], 0, 0, 0);
                }
        }
    }
    const int gm0 = blockIdx.y * 128 + wm;
#pragma unroll
    for (int i = 0; i < 4; ++i)
#pragma unroll
        for (int j = 0; j < 4; ++j) {
            int gn = wn + 16 * j + ln;
            float bc = bg1[gn];
#pragma unroll
            for (int r = 0; r < 4; ++r) {
                int gm = gm0 + 16 * i + q * 4 + r;
                g[(size_t)gm * GHID + gn] = fmaxf(acc[i][j][r] + bc, 0.f);
            }
        }
}

// ---------- gating: logits -> softmax -> top2 -> normalized gates (fp32) ----------
__global__ __launch_bounds__(256) void gating(
    const float* __restrict__ g, const float* __restrict__ Wg2, const float* __restrict__ bg2,
    float* __restrict__ gates, int* __restrict__ esel) {
    int wv = threadIdx.x >> 6, lane = threadIdx.x & 63;
    int n = blockIdx.x * 4 + wv;
    float p[NEXP];
    float g1 = g[(size_t)n * GHID + lane];
    float g2 = g[(size_t)n * GHID + 64 + lane];
#pragma unroll
    for (int e = 0; e < NEXP; ++e)
        p[e] = g1 * Wg2[lane * NEXP + e] + g2 * Wg2[(64 + lane) * NEXP + e];
#pragma unroll
    for (int off = 32; off > 0; off >>= 1)
#pragma unroll
        for (int e = 0; e < NEXP; ++e) p[e] += __shfl_xor(p[e], off, 64);
    if (lane == 0) {
        float l[NEXP], mx = -1e30f;
#pragma unroll
        for (int e = 0; e < NEXP; ++e) { l[e] = p[e] + bg2[e]; mx = fmaxf(mx, l[e]); }
        float pr[NEXP], s = 0.f;
#pragma unroll
        for (int e = 0; e < NEXP; ++e) { pr[e] = expf(l[e] - mx); s += pr[e]; }
#pragma unroll
        for (int e = 0; e < NEXP; ++e) pr[e] /= s;
        int i0 = 0;
#pragma unroll
        for (int e = 1; e < NEXP; ++e) if (pr[e] > pr[i0]) i0 = e;
        int i1 = -1;
#pragma unroll
        for (int e = 0; e < NEXP; ++e) if (e != i0 && (i1 < 0 || pr[e] > pr[i1])) i1 = e;
        float v0 = pr[i0], v1 = pr[i1], s2 = v0 + v1;
        gates[2 * n]     = v0 / s2;
        gates[2 * n + 1] = v1 / s2;
        esel[2 * n]      = i0;
        esel[2 * n + 1]  = i1;
    }
}

// ---------- slot machinery: per-(expert,rank) 128-padded compaction ----------
__global__ __launch_bounds__(256) void slot_count(const int* __restrict__ esel,
                                                  int* __restrict__ slotcnt) {
    __shared__ int h[10];
    if (threadIdx.x < 10) h[threadIdx.x] = 0;
    __syncthreads();
    int n = blockIdx.x * 256 + threadIdx.x;
    if (n < NNODE) {
        atomicAdd(&h[esel[2 * n] * 2 + 0], 1);
        atomicAdd(&h[esel[2 * n + 1] * 2 + 1], 1);
    }
    __syncthreads();
    if (threadIdx.x < 10) atomicAdd(&slotcnt[threadIdx.x], h[threadIdx.x]);
}
// header: [0]=tiles_all, [1]=tiles_rank0, [2]=tiles_rank1
__global__ void seg_plan(const int* __restrict__ slotcnt, int* __restrict__ cursor,
                         int* __restrict__ header, int2* __restrict__ meta_all,
                         int2* __restrict__ meta_r0, int2* __restrict__ meta_r1) {
    if (threadIdx.x == 0 && blockIdx.x == 0) {
        int base = 0, ta = 0, t0 = 0, t1 = 0;
        for (int s = 0; s < 10; ++s) {
            cursor[s] = base;
            int nt = (slotcnt[s] + 127) >> 7;
            for (int k = 0; k < nt; ++k) {
                int2 m; m.x = s; m.y = base + k * 128;
                meta_all[ta++] = m;
                if (s & 1) meta_r1[t1++] = m; else meta_r0[t0++] = m;
            }
            base += nt * 128;
        }
        header[0] = ta; header[1] = t0; header[2] = t1;
    }
}
__global__ __launch_bounds__(256) void slot_fill(
    const int* __restrict__ esel, const float* __restrict__ gates, int* __restrict__ cursor,
    int* __restrict__ rowlist, float* __restrict__ gateval) {
    __shared__ int h[10], base[10];
    if (threadIdx.x < 10) h[threadIdx.x] = 0;
    __syncthreads();
    int n = blockIdx.x * 256 + threadIdx.x;
    int s0 = 0, s1 = 0, p0 = 0, p1 = 0;
    bool on = (n < NNODE);
    if (on) {
        s0 = esel[2 * n] * 2;
        s1 = esel[2 * n + 1] * 2 + 1;
        p0 = atomicAdd(&h[s0], 1);
        p1 = atomicAdd(&h[s1], 1);
    }
    __syncthreads();
    if (threadIdx.x < 10) base[threadIdx.x] = atomicAdd(&cursor[threadIdx.x], h[threadIdx.x]);
    __syncthreads();
    if (on) {
        int q0 = base[s0] + p0, q1 = base[s1] + p1;
        rowlist[q0] = n; gateval[q0] = gates[2 * n];
        rowlist[q1] = n; gateval[q1] = gates[2 * n + 1];
    }
}

// ---------- expert layer 1 (compacted): h1[slot] = gelu(x[rowlist[slot]] @ We1[e] + be1[e]) ----------
__global__ __launch_bounds__(256) void gemm_moe1(
    const float* __restrict__ xtab, const float* __restrict__ xstr, const float* __restrict__ xtxt,
    const unsigned short* __restrict__ We1t, const float* __restrict__ be1,
    const int* __restrict__ header, const int2* __restrict__ meta,
    const int* __restrict__ rowlist, unsigned short* __restrict__ h1) {
    if ((int)blockIdx.y >= header[0]) return;
    __shared__ unsigned short As[128 * 64];
    __shared__ unsigned short Bs[128 * 64];
    int2 mt = meta[blockIdx.y];
    const int eid = mt.x >> 1, rowbase = mt.y;
    const float* xf = (eid == 0) ? xtab : ((eid == 1 || eid == 4) ? xstr : xtxt);
    const int t = threadIdx.x, w = t >> 6, lane = t & 63;
    const int ln = lane & 15, q = lane >> 4;
    const int wm = (w >> 1) * 64, wn = (w & 1) * 64;
    const int rb = w * 8 + (lane >> 3), kg = lane & 7;
    const int koff = (kg ^ (rb & 7)) * 8;
    int rows[4];
#pragma unroll
    for (int it = 0; it < 4; ++it) {
        int rr = rowlist[rowbase + rb + 32 * it];
        rows[it] = (rr < 0) ? 0 : rr;
    }
    const unsigned short* Bg = We1t + (size_t)eid * HDIM * EDIM
                             + (size_t)(blockIdx.x * 128 + rb) * EDIM + koff;
    unsigned short* Bl = &Bs[rb * 64 + kg * 8];
    float4v acc[4][4];
#pragma unroll
    for (int i = 0; i < 4; ++i)
#pragma unroll
        for (int j = 0; j < 4; ++j) acc[i][j] = (float4v){0.f, 0.f, 0.f, 0.f};

    for (int kt = 0; kt < EDIM; kt += 64) {
        __syncthreads();
#pragma unroll
        for (int it = 0; it < 4; ++it) {
            const float* sp = xf + (size_t)rows[it] * EDIM + kt + koff;
            float4v a0 = *(const float4v*)sp;
            float4v a1 = *(const float4v*)(sp + 4);
            union { short8 v; unsigned short s[8]; } pk;
#pragma unroll
            for (int c = 0; c < 4; ++c) { pk.s[c] = f2b(a0[c]); pk.s[4 + c] = f2b(a1[c]); }
            *(short8*)&As[(rb + 32 * it) * 64 + kg * 8] = pk.v;
            gl_lds16(Bg + (size_t)it * 32 * EDIM + kt, Bl + it * 32 * 64);
        }
        __syncthreads();
#pragma unroll
        for (int kk = 0; kk < 2; ++kk) {
            short8 af[4], bf[4];
#pragma unroll
            for (int i = 0; i < 4; ++i)
                af[i] = *(const short8*)&As[(wm + 16 * i + ln) * 64 + (((kk * 4 + q) ^ (ln & 7)) * 8)];
#pragma unroll
            for (int j = 0; j < 4; ++j)
                bf[j] = *(const short8*)&Bs[(wn + 16 * j + ln) * 64 + (((kk * 4 + q) ^ (ln & 7)) * 8)];
#pragma unroll
            for (int i = 0; i < 4; ++i)
#pragma unroll
                for (int j = 0; j < 4; ++j)
                    acc[i][j] = __builtin_amdgcn_mfma_f32_16x16x32_bf16(af[i], bf[j], acc[i][j], 0, 0, 0);
        }
    }
    const int gn0 = blockIdx.x * 128 + wn;
#pragma unroll
    for (int i = 0; i < 4; ++i)
#pragma unroll
        for (int j = 0; j < 4; ++j) {
            int gn = gn0 + 16 * j + ln;
            float bc = be1[eid * HDIM + gn];
#pragma unroll
            for (int r = 0; r < 4; ++r) {
                int slot = rowbase + wm + 16 * i + q * 4 + r;
                h1[(size_t)slot * HDIM + gn] = f2b(gelu_tanh(acc[i][j][r] + bc));
            }
        }
}

// ---------- expert layer 2 (compacted, scatter): nf[node] (+)= gate*(h1[slot]@We2[e] + be2[e]) ----------
template<int RMW>
__global__ __launch_bounds__(256) void gemm_moe2(
    const unsigned short* __restrict__ h1, const unsigned short* __restrict__ We2t,
    const float* __restrict__ be2, const int* __restrict__ header,
    const int2* __restrict__ meta, const int* __restrict__ rowlist,
    const float* __restrict__ gateval, unsigned short* __restrict__ nf) {
    if ((int)blockIdx.y >= header[RMW ? 2 : 1]) return;
    __shared__ unsigned short As[128 * 64];
    __shared__ unsigned short Bs[128 * 64];
    int2 mt = meta[blockIdx.y];
    const int eid = mt.x >> 1, rowbase = mt.y;
    const int t = threadIdx.x, w = t >> 6, lane = t & 63;
    const int ln = lane & 15, q = lane >> 4;
    const int wm = (w >> 1) * 64, wn = (w & 1) * 64;
    const int rb = w * 8 + (lane >> 3), kg = lane & 7;
    const int koff = (kg ^ (rb & 7)) * 8;
    const unsigned short* Ag = h1 + (size_t)(rowbase + rb) * HDIM + koff;
    const unsigned short* Bg = We2t + (size_t)eid * HDIM * HDIM
                             + (size_t)(blockIdx.x * 128 + rb) * HDIM + koff;
    unsigned short* Al = &As[rb * 64 + kg * 8];
    unsigned short* Bl = &Bs[rb * 64 + kg * 8];
    float4v acc[4][4];
#pragma unroll
    for (int i = 0; i < 4; ++i)
#pragma unroll
        for (int j = 0; j < 4; ++j) acc[i][j] = (float4v){0.f, 0.f, 0.f, 0.f};

    for (int kt = 0; kt < HDIM; kt += 64) {
        __syncthreads();
#pragma unroll
        for (int it = 0; it < 4; ++it) {
            gl_lds16(Ag + (size_t)it * 32 * HDIM + kt, Al + it * 32 * 64);
            gl_lds16(Bg + (size_t)it * 32 * HDIM + kt, Bl + it * 32 * 64);
        }
        __syncthreads();
#pragma unroll
        for (int kk = 0; kk < 2; ++kk) {
            short8 af[4], bf[4];
#pragma unroll
            for (int i = 0; i < 4; ++i)
                af[i] = *(const short8*)&As[(wm + 16 * i + ln) * 64 + (((kk * 4 + q) ^ (ln & 7)) * 8)];
#pragma unroll
            for (int j = 0; j < 4; ++j)
                bf[j] = *(const short8*)&Bs[(wn + 16 * j + ln) * 64 + (((kk * 4 + q) ^ (ln & 7)) * 8)];
#pragma unroll
            for (int i = 0; i < 4; ++i)
#pragma unroll
                for (int j = 0; j < 4; ++j)
                    acc[i][j] = __builtin_amdgcn_mfma_f32_16x16x32_bf16(af[i], bf[j], acc[i][j], 0, 0, 0);
        }
    }
    const int gn0 = blockIdx.x * 128 + wn;
#pragma unroll
    for (int i = 0; i < 4; ++i)
#pragma unroll
        for (int r = 0; r < 4; ++r) {
            int slot = rowbase + wm + 16 * i + q * 4 + r;
            int node = rowlist[slot];
            if (node >= 0) {
                float gt = gateval[slot];
#pragma unroll
                for (int j = 0; j < 4; ++j) {
                    int gn = gn0 + 16 * j + ln;
                    size_t o = (size_t)node * HDIM + gn;
                    float v = gt * (acc[i][j][r] + be2[eid * HDIM + gn]);
                    nf[o] = RMW ? f2b(b2f(nf[o]) + v) : f2b(v);
                }
            }
        }
}

// ---------- GNN fused layer: C = relu([h, agg] @ [Wself; Wnbr])  (K=1024 concat) ----------
template<int FINAL>
__global__ __launch_bounds__(256) void gemm_gnn(
    const unsigned short* __restrict__ A0, const unsigned short* __restrict__ A1,
    const unsigned short* __restrict__ Bt, unsigned short* __restrict__ Cb,
    float* __restrict__ Cf) {
    __shared__ unsigned short As[128 * 64];
    __shared__ unsigned short Bs[128 * 64];
    const int t = threadIdx.x, w = t >> 6, lane = t & 63;
    const int ln = lane & 15, q = lane >> 4;
    const int wm = (w >> 1) * 64, wn = (w & 1) * 64;
    const int rb = w * 8 + (lane >> 3), kg = lane & 7;
    const int koff = (kg ^ (rb & 7)) * 8;
    const unsigned short* Ag0 = A0 + (size_t)(blockIdx.y * 128 + rb) * HDIM + koff;
    const unsigned short* Ag1 = A1 + (size_t)(blockIdx.y * 128 + rb) * HDIM + koff;
    const unsigned short* Bg  = Bt + (size_t)(blockIdx.x * 128 + rb) * 1024 + koff;
    unsigned short* Al = &As[rb * 64 + kg * 8];
    unsigned short* Bl = &Bs[rb * 64 + kg * 8];
    float4v acc[4][4];
#pragma unroll
    for (int i = 0; i < 4; ++i)
#pragma unroll
        for (int j = 0; j < 4; ++j) acc[i][j] = (float4v){0.f, 0.f, 0.f, 0.f};

    for (int kt = 0; kt < 1024; kt += 64) {
        __syncthreads();
#pragma unroll
        for (int it = 0; it < 4; ++it) {
            const unsigned short* asrc = (kt < HDIM)
                ? (Ag0 + (size_t)it * 32 * HDIM + kt)
                : (Ag1 + (size_t)it * 32 * HDIM + (kt - HDIM));
            gl_lds16(asrc, Al + it * 32 * 64);
            gl_lds16(Bg + (size_t)it * 32 * 1024 + kt, Bl + it * 32 * 64);
        }
        __syncthreads();
#pragma unroll
        for (int kk = 0; kk < 2; ++kk) {
            short8 af[4], bf[4];
#pragma unroll
            for (int i = 0; i < 4; ++i)
                af[i] = *(const short8*)&As[(wm + 16 * i + ln) * 64 + (((kk * 4 + q) ^ (ln & 7)) * 8)];
#pragma unroll
            for (int j = 0; j < 4; ++j)
                bf[j] = *(const short8*)&Bs[(wn + 16 * j + ln) * 64 + (((kk * 4 + q) ^ (ln & 7)) * 8)];
#pragma unroll
            for (int i = 0; i < 4; ++i)
#pragma unroll
                for (int j = 0; j < 4; ++j)
                    acc[i][j] = __builtin_amdgcn_mfma_f32_16x16x32_bf16(af[i], bf[j], acc[i][j], 0, 0, 0);
        }
    }
    const int gm0 = blockIdx.y * 128 + wm;
    const int gn0 = blockIdx.x * 128 + wn;
#pragma unroll
    for (int i = 0; i < 4; ++i)
#pragma unroll
        for (int j = 0; j < 4; ++j) {
            int gn = gn0 + 16 * j + ln;
#pragma unroll
            for (int r = 0; r < 4; ++r) {
                int gm = gm0 + 16 * i + q * 4 + r;
                float v = fmaxf(acc[i][j][r], 0.f);
                if (FINAL) {
                    if (gm < NNODE) Cf[(size_t)gm * HDIM + gn] = v;
                } else {
                    Cb[(size_t)gm * HDIM + gn] = f2b(v);
                }
            }
        }
}

// ---------- CSR build ----------
__global__ void hist_kernel(const int* __restrict__ dst, int* __restrict__ deg) {
    int i = blockIdx.x * blockDim.x + threadIdx.x;
    if (i < NEDGE) atomicAdd(&deg[dst[i]], 1);
}
__global__ void scan_block(const int* __restrict__ in, int* __restrict__ incl,
                           int* __restrict__ bsum, int n) {
    __shared__ int s[256];
    int i = blockIdx.x * 256 + threadIdx.x;
    s[threadIdx.x] = (i < n) ? in[i] : 0;
    __syncthreads();
    for (int off = 1; off < 256; off <<= 1) {
        int t = (threadIdx.x >= (unsigned)off) ? s[threadIdx.x - off] : 0;
        __syncthreads();
        s[threadIdx.x] += t;
        __syncthreads();
    }
    if (i < n) incl[i] = s[threadIdx.x];
    if (bsum != nullptr && threadIdx.x == 255) bsum[blockIdx.x] = s[255];
}
__global__ void scan_fix(const int* __restrict__ incl, const int* __restrict__ deg,
                         const int* __restrict__ bscan, int* __restrict__ rowstart,
                         int* __restrict__ ecur) {
    int i = blockIdx.x * blockDim.x + threadIdx.x;
    if (i < NNODE) {
        int b = i >> 8;
        int add = (b > 0) ? bscan[b - 1] : 0;
        int st = incl[i] - deg[i] + add;
        rowstart[i] = st;
        ecur[i] = st;
    }
}
__global__ void fill_csr(const int* __restrict__ src, const int* __restrict__ dst,
                         int* __restrict__ ecur, int* __restrict__ srcs) {
    int e = blockIdx.x * blockDim.x + threadIdx.x;
    if (e < NEDGE) {
        int pos = atomicAdd(&ecur[dst[e]], 1);
        srcs[pos] = src[e];
    }
}

// ---------- segment-sum of bf16 rows -> bf16: agg[n] = sum_{s in nbrs(n)} h[s] ----------
// One wave per node (4 nodes/block). No LDS, no barriers. Round-1 proven version:
// at the fabric ceiling (~3.6 TB/s L2-miss path) for this random 1KB-row gather.
__global__ __launch_bounds__(256) void msg_sum_w(
    const unsigned short* __restrict__ h, const int* __restrict__ rowstart,
    const int* __restrict__ deg, const int* __restrict__ srcs,
    unsigned short* __restrict__ agg) {
    const int wv = threadIdx.x >> 6, lane = threadIdx.x & 63;
    const int n = blockIdx.x * 4 + wv;
    const int st = rowstart[n], d = deg[n];
    float acc[8] = {0.f,0.f,0.f,0.f,0.f,0.f,0.f,0.f};
    const unsigned short* hp = h + (size_t)lane * 8;
    for (int cb = 0; cb < d; cb += 64) {
        int cnt = d - cb; if (cnt > 64) cnt = 64;
        int sidx = (cb + lane < d) ? srcs[st + cb + lane] : 0;
        int t = 0;
        for (; t + 4 <= cnt; t += 4) {
            int s0 = __shfl(sidx, t,     64);
            int s1 = __shfl(sidx, t + 1, 64);
            int s2 = __shfl(sidx, t + 2, 64);
            int s3 = __shfl(sidx, t + 3, 64);
            short8 v0 = *(const short8*)(hp + (size_t)s0 * HDIM);
            short8 v1 = *(const short8*)(hp + (size_t)s1 * HDIM);
            short8 v2 = *(const short8*)(hp + (size_t)s2 * HDIM);
            short8 v3 = *(const short8*)(hp + (size_t)s3 * HDIM);
#pragma unroll
            for (int c = 0; c < 8; ++c)
                acc[c] += (b2f((unsigned short)v0[c]) + b2f((unsigned short)v1[c]))
                        + (b2f((unsigned short)v2[c]) + b2f((unsigned short)v3[c]));
        }
        for (; t < cnt; ++t) {
            int s = __shfl(sidx, t, 64);
            short8 v = *(const short8*)(hp + (size_t)s * HDIM);
#pragma unroll
            for (int c = 0; c < 8; ++c) acc[c] += b2f((unsigned short)v[c]);
        }
    }
    union { short8 v; unsigned short s[8]; } o;
#pragma unroll
    for (int c = 0; c < 8; ++c) o.s[c] = f2b(acc[c]);
    *(short8*)(agg + (size_t)n * HDIM + lane * 8) = o.v;
}

extern "C" void kernel_launch(void* const* d_in, const int* in_sizes, int n_in,
                              void* d_out, int out_size, void* d_ws, size_t ws_size,
                              hipStream_t stream) {
    (void)in_sizes; (void)n_in; (void)out_size; (void)ws_size;
    const float* text       = (const float*)d_in[0];
    const float* tabular    = (const float*)d_in[1];
    const float* structured = (const float*)d_in[2];
    const int*   e_in       = (const int*)d_in[3];
    const float* Wg1  = (const float*)d_in[4];
    const float* bg1  = (const float*)d_in[5];
    const float* Wg2  = (const float*)d_in[6];
    const float* bg2  = (const float*)d_in[7];
    const float* We1  = (const float*)d_in[8];
    const float* be1  = (const float*)d_in[9];
    const float* We2  = (const float*)d_in[10];
    const float* be2  = (const float*)d_in[11];
    const float* Wself = (const float*)d_in[12];
    const float* Wnbr  = (const float*)d_in[13];
    const int* src = e_in;
    const int* dst = e_in + NEDGE;
    float* dout = (float*)d_out;

    // ---- workspace carve-up (regions overlap across phases; ~220 MB total) ----
    char* w = (char*)d_ws;
    auto alloc = [&](size_t bytes) { char* p = w; w += (bytes + 511) & ~(size_t)511; return p; };
    const size_t SZ_H = (size_t)M_PAD * HDIM * 2;            // 51.25 MB
    unsigned short* We1t  = (unsigned short*)alloc((size_t)NEXP * HDIM * EDIM * 2);
    unsigned short* We2t  = (unsigned short*)alloc((size_t)NEXP * HDIM * HDIM * 2);
    unsigned short* Wcat0 = (unsigned short*)alloc((size_t)HDIM * 1024 * 2);
    unsigned short* Wcat1 = (unsigned short*)alloc((size_t)HDIM * 1024 * 2);
    unsigned short* Wg1h  = (unsigned short*)alloc((size_t)GHID * 768 * 2);
    unsigned short* Wg1l  = (unsigned short*)alloc((size_t)GHID * 768 * 2);
    float* gates    = (float*)alloc((size_t)NNODE * 2 * 4);
    int*   esel     = (int*)alloc((size_t)NNODE * 2 * 4);
    int*   slotcnt  = (int*)alloc(16 * 4);
    int*   scursor  = (int*)alloc(16 * 4);
    int*   header   = (int*)alloc(16 * 4);
    int2*  meta_all = (int2*)alloc((size_t)MAXT_ALL * 8);
    int2*  meta_r0  = (int2*)alloc((size_t)MAXT_R * 8);
    int2*  meta_r1  = (int2*)alloc((size_t)MAXT_R * 8);
    int*   rowlist  = (int*)alloc((size_t)SLOTCAP * 4);
    float* gateval  = (float*)alloc((size_t)SLOTCAP * 4);
    int*   deg      = (int*)alloc((size_t)NNODE * 4);
    int*   incl     = (int*)alloc((size_t)NNODE * 4);
    int*   bsum     = (int*)alloc(1024 * 4);
    int*   bscan    = (int*)alloc(1024 * 4);
    int*   rowstart = (int*)alloc((size_t)NNODE * 4);
    int*   ecur     = (int*)alloc((size_t)NNODE * 4);
    int*   srcs     = (int*)alloc((size_t)NEDGE * 4);
    unsigned short* nfb = (unsigned short*)alloc(SZ_H);
    // region A: gbuf (gate hidden, fp32) dead after gating; aggb alive only in GNN
    char* regA = alloc((size_t)M_PAD * GHID * 4 > SZ_H ? (size_t)M_PAD * GHID * 4 : SZ_H);
    float*          gbuf = (float*)regA;
    unsigned short* aggb = (unsigned short*)regA;
    // region B: h1c (compacted expert hidden) dead after moe2; hb alive only in GNN
    char* regB = alloc((size_t)SLOTCAP * HDIM * 2);
    unsigned short* h1c = (unsigned short*)regB;
    unsigned short* hb  = (unsigned short*)regB;

    // ---- weight prep: single fused kernel (was 7 launches) ----
    wprep<<<1024, 256, 0, stream>>>(We1, We2, Wself, Wnbr, Wg1,
                                    We1t, We2t, Wcat0, Wcat1, Wg1h, Wg1l);

    hipMemsetAsync(slotcnt, 0, 16 * 4, stream);
    hipMemsetAsync(rowlist, 0xFF, (size_t)SLOTCAP * 4, stream);
    hipMemsetAsync(deg, 0, (size_t)NNODE * 4, stream);

    // ---- gate (bf16x3 split, fp32 fidelity) + routing ----
    gate128<<<dim3(1, M_PAD / 128), 256, 0, stream>>>(text, tabular, structured,
                                                      Wg1h, Wg1l, bg1, gbuf);
    gating<<<NNODE / 4, 256, 0, stream>>>(gbuf, Wg2, bg2, gates, esel);

    // ---- compaction plan ----
    slot_count<<<(NNODE + 255) / 256, 256, 0, stream>>>(esel, slotcnt);
    seg_plan<<<1, 64, 0, stream>>>(slotcnt, scursor, header, meta_all, meta_r0, meta_r1);
    slot_fill<<<(NNODE + 255) / 256, 256, 0, stream>>>(esel, gates, scursor, rowlist, gateval);

    // ---- experts on routed rows only ----
    gemm_moe1<<<dim3(HDIM / 128, MAXT_ALL), 256, 0, stream>>>(
        tabular, structured, text, We1t, be1, header, meta_all, rowlist, h1c);
    gemm_moe2<0><<<dim3(HDIM / 128, MAXT_R), 256, 0, stream>>>(
        h1c, We2t, be2, header, meta_r0, rowlist, gateval, nfb);
    gemm_moe2<1><<<dim3(HDIM / 128, MAXT_R), 256, 0, stream>>>(
        h1c, We2t, be2, header, meta_r1, rowlist, gateval, nfb);

    // ---- CSR of edges grouped by dst ----
    const int NB = (NNODE + 255) / 256;
    hist_kernel<<<(NEDGE + 255) / 256, 256, 0, stream>>>(dst, deg);
    scan_block<<<NB, 256, 0, stream>>>(deg, incl, bsum, NNODE);
    scan_block<<<1, 256, 0, stream>>>(bsum, bscan, nullptr, NB);
    scan_fix<<<NB, 256, 0, stream>>>(incl, deg, bscan, rowstart, ecur);
    fill_csr<<<(NEDGE + 255) / 256, 256, 0, stream>>>(src, dst, ecur, srcs);

    // ---- GNN layer 0: agg = segsum(nf); h = relu([nf,agg] @ Wcat0) ----
    msg_sum_w<<<NNODE / 4, 256, 0, stream>>>(nfb, rowstart, deg, srcs, aggb);
    gemm_gnn<0><<<dim3(HDIM / 128, M_PAD / 128), 256, 0, stream>>>(nfb, aggb, Wcat0, hb, nullptr);

    // ---- GNN layer 1: agg = segsum(h); out = relu([h,agg] @ Wcat1) ----
    msg_sum_w<<<NNODE / 4, 256, 0, stream>>>(hb, rowstart, deg, srcs, aggb);
    gemm_gnn<1><<<dim3(HDIM / 128, M_PAD / 128), 256, 0, stream>>>(hb, aggb, Wcat1, nullptr, dout);
}

// Round 4
// 1048.422 us; speedup vs baseline: 1.8707x; 1.0502x over previous
//
#include <hip/hip_runtime.h>
#include <hip/hip_bf16.h>

#define NNODE 50000
#define M_PAD 50048
#define EDIM  256
#define HDIM  512
#define NEXP  5
#define GHID  128
#define NEDGE 800000
#define SLOTCAP 101504   // >= 2*NNODE + 10*127, 128-aligned
#define MAXT_ALL 792     // max (expert,rank) tiles total
#define MAXT_R   396     // max tiles per rank

typedef __attribute__((ext_vector_type(8))) short  short8;
typedef __attribute__((ext_vector_type(4))) float  float4v;
typedef __attribute__((ext_vector_type(4))) unsigned short ushort4v;

typedef __attribute__((address_space(1))) const unsigned int gas_u32;
typedef __attribute__((address_space(3))) unsigned int       las_u32;

__device__ __forceinline__ void gl_lds16(const unsigned short* g, unsigned short* l) {
    __builtin_amdgcn_global_load_lds((gas_u32*)g, (las_u32*)l, 16, 0, 0);
}
__device__ __forceinline__ unsigned short f2b(float f) {
    unsigned u = __builtin_bit_cast(unsigned, f);
    u += 0x7FFFu + ((u >> 16) & 1u);
    return (unsigned short)(u >> 16);
}
__device__ __forceinline__ float b2f(unsigned short h) {
    unsigned u = ((unsigned)h) << 16;
    return __builtin_bit_cast(float, u);
}
__device__ __forceinline__ float fast_tanh(float y) {
    float ay = fabsf(y);
    float e  = __expf(-2.0f * ay);
    float t  = (1.0f - e) / (1.0f + e);
    return (y < 0.0f) ? -t : t;
}
__device__ __forceinline__ float gelu_tanh(float x) {
    float inner = 0.7978845608028654f * (x + 0.044715f * x * x * x);
    return 0.5f * x * (1.0f + fast_tanh(inner));
}

// ---------- unified weight prep + workspace init: one kernel, no memsets ----------
// Segment map (compile-time, element index i):
//  [0, 655360)           We1t  [5][512c][256r]   <- We1[5][256r][512c]
//  [655360, 1966080)     We2t  [5][512c][512r]   <- We2[5][512r][512c]
//  [1966080, 3014656)    Wcat0/Wcat1 quarters    <- Wself[2]/Wnbr[2] (ld 1024, ko 0/512)
//  [3014656, 3112960)    Wg1h/Wg1l hi/lo split   <- Wg1[768r][128c]
//  [3112960, +SLOTCAP)   rowlist = -1
//  [.., +NNODE)          deg = 0
//  [.., +16)             slotcnt = 0
#define WP_N0 655360
#define WP_C1 1966080
#define WP_C2 3014656
#define WP_TOT 3112960
#define WP_T_RL  WP_TOT
#define WP_T_DEG (WP_TOT + SLOTCAP)
#define WP_T_SC  (WP_TOT + SLOTCAP + NNODE)
#define WP_ALL   (WP_TOT + SLOTCAP + NNODE + 16)
__global__ __launch_bounds__(256) void wprep(
    const float* __restrict__ We1, const float* __restrict__ We2,
    const float* __restrict__ Wself, const float* __restrict__ Wnbr,
    const float* __restrict__ Wg1,
    unsigned short* __restrict__ We1t, unsigned short* __restrict__ We2t,
    unsigned short* __restrict__ Wcat0, unsigned short* __restrict__ Wcat1,
    unsigned short* __restrict__ Wg1h, unsigned short* __restrict__ Wg1l,
    int* __restrict__ rowlist, int* __restrict__ deg, int* __restrict__ slotcnt) {
    for (int i = blockIdx.x * blockDim.x + threadIdx.x; i < WP_ALL;
         i += gridDim.x * blockDim.x) {
        if (i < WP_N0) {                      // We1t: B=5, R=256, C=512
            int b = i >> 17, rem = i & 131071;
            int c = rem >> 8, r = rem & 255;
            We1t[i] = f2b(We1[(size_t)b * 131072 + (size_t)r * 512 + c]);
        } else if (i < WP_C1) {               // We2t: B=5, R=512, C=512
            int j = i - WP_N0;
            int b = j >> 18, rem = j & 262143;
            int c = rem >> 9, r = rem & 511;
            We2t[j] = f2b(We2[(size_t)b * 262144 + (size_t)r * 512 + c]);
        } else if (i < WP_C2) {               // Wcat quarters: R=C=512, ldo=1024
            int j = i - WP_C1;
            int qd = j >> 18, k = j & 262143;
            int c = k >> 9, r = k & 511;
            const float* in = (qd & 1) ? Wnbr : Wself;
            if (qd >> 1) in += 262144;        // layer 1
            unsigned short* out = (qd >> 1) ? Wcat1 : Wcat0;
            int ko = (qd & 1) * 512;
            out[(size_t)c * 1024 + ko + r] = f2b(in[(size_t)r * 512 + c]);
        } else if (i < WP_TOT) {              // Wg1 hi/lo: R=768, C=128
            int j = i - WP_C2;
            int c = j / 768, r = j - c * 768;
            float f = Wg1[(size_t)r * 128 + c];
            unsigned short hi = f2b(f);
            Wg1h[j] = hi;
            Wg1l[j] = f2b(f - b2f(hi));
        } else if (i < WP_T_DEG) {
            rowlist[i - WP_T_RL] = -1;
        } else if (i < WP_T_SC) {
            deg[i - WP_T_DEG] = 0;
        } else {
            slotcnt[i - WP_T_SC] = 0;
        }
    }
}

// ---------- gate layer 1, bf16x3 split MFMA: g = relu(concat(text,tab,str) @ Wg1 + bg1) ----------
__global__ __launch_bounds__(256) void gate128(
    const float* __restrict__ xtxt, const float* __restrict__ xtab, const float* __restrict__ xstr,
    const unsigned short* __restrict__ Bh, const unsigned short* __restrict__ Blo,
    const float* __restrict__ bg1, float* __restrict__ g) {
    __shared__ unsigned short Ash[128 * 64];
    __shared__ unsigned short Asl[128 * 64];
    __shared__ unsigned short Bsh[128 * 64];
    __shared__ unsigned short Bsl[128 * 64];
    const int t = threadIdx.x, w = t >> 6, lane = t & 63;
    const int ln = lane & 15, q = lane >> 4;
    const int wm = (w >> 1) * 64, wn = (w & 1) * 64;
    const int rb = w * 8 + (lane >> 3), kg = lane & 7;
    const int koff = (kg ^ (rb & 7)) * 8;
    const float* xs[3] = { xtxt, xtab, xstr };
    const unsigned short* Bgh = Bh  + (size_t)rb * 768 + koff;
    const unsigned short* Bgl = Blo + (size_t)rb * 768 + koff;
    unsigned short* Blh = &Bsh[rb * 64 + kg * 8];
    unsigned short* Bll = &Bsl[rb * 64 + kg * 8];
    float4v acc[4][4];
#pragma unroll
    for (int i = 0; i < 4; ++i)
#pragma unroll
        for (int j = 0; j < 4; ++j) acc[i][j] = (float4v){0.f, 0.f, 0.f, 0.f};

    for (int kt = 0; kt < 768; kt += 64) {
        const float* xp = xs[kt >> 8];
        const int kloc = kt & 255;
        __syncthreads();
#pragma unroll
        for (int it = 0; it < 4; ++it) {
            int row = blockIdx.y * 128 + rb + 32 * it;
            union { short8 v; unsigned short s[8]; } ph, pl;
            if (row < NNODE) {
                const float* sp = xp + (size_t)row * EDIM + kloc + koff;
                float4v a0 = *(const float4v*)sp;
                float4v a1 = *(const float4v*)(sp + 4);
#pragma unroll
                for (int c = 0; c < 4; ++c) {
                    unsigned short h0 = f2b(a0[c]);
                    ph.s[c] = h0; pl.s[c] = f2b(a0[c] - b2f(h0));
                    unsigned short h1 = f2b(a1[c]);
                    ph.s[4 + c] = h1; pl.s[4 + c] = f2b(a1[c] - b2f(h1));
                }
            } else {
#pragma unroll
                for (int c = 0; c < 8; ++c) { ph.s[c] = 0; pl.s[c] = 0; }
            }
            *(short8*)&Ash[(rb + 32 * it) * 64 + kg * 8] = ph.v;
            *(short8*)&Asl[(rb + 32 * it) * 64 + kg * 8] = pl.v;
            gl_lds16(Bgh + (size_t)it * 32 * 768 + kt, Blh + it * 32 * 64);
            gl_lds16(Bgl + (size_t)it * 32 * 768 + kt, Bll + it * 32 * 64);
        }
        __syncthreads();
#pragma unroll
        for (int kk = 0; kk < 2; ++kk) {
            short8 ah[4], al[4], bh[4], bl[4];
#pragma unroll
            for (int i = 0; i < 4; ++i) {
                int off = (wm + 16 * i + ln) * 64 + (((kk * 4 + q) ^ (ln & 7)) * 8);
                ah[i] = *(const short8*)&Ash[off];
                al[i] = *(const short8*)&Asl[off];
            }
#pragma unroll
            for (int j = 0; j < 4; ++j) {
                int off = (wn + 16 * j + ln) * 64 + (((kk * 4 + q) ^ (ln & 7)) * 8);
                bh[j] = *(const short8*)&Bsh[off];
                bl[j] = *(const short8*)&Bsl[off];
            }
#pragma unroll
            for (int i = 0; i < 4; ++i)
#pragma unroll
                for (int j = 0; j < 4; ++j) {
                    acc[i][j] = __builtin_amdgcn_mfma_f32_16x16x32_bf16(ah[i], bh[j], acc[i][j], 0, 0, 0);
                    acc[i][j] = __builtin_amdgcn_mfma_f32_16x16x32_bf16(ah[i], bl[j], acc[i][j], 0, 0, 0);
                    acc[i][j] = __builtin_amdgcn_mfma_f32_16x16x32_bf16(al[i], bh[j], acc[i][j], 0, 0, 0);
                }
        }
    }
    const int gm0 = blockIdx.y * 128 + wm;
#pragma unroll
    for (int i = 0; i < 4; ++i)
#pragma unroll
        for (int j = 0; j < 4; ++j) {
            int gn = wn + 16 * j + ln;
            float bc = bg1[gn];
#pragma unroll
            for (int r = 0; r < 4; ++r) {
                int gm = gm0 + 16 * i + q * 4 + r;
                g[(size_t)gm * GHID + gn] = fmaxf(acc[i][j][r] + bc, 0.f);
            }
        }
}

// ---------- gating: logits -> softmax -> top2 -> normalized gates (fp32) ----------
__global__ __launch_bounds__(256) void gating(
    const float* __restrict__ g, const float* __restrict__ Wg2, const float* __restrict__ bg2,
    float* __restrict__ gates, int* __restrict__ esel) {
    int wv = threadIdx.x >> 6, lane = threadIdx.x & 63;
    int n = blockIdx.x * 4 + wv;
    float p[NEXP];
    float g1 = g[(size_t)n * GHID + lane];
    float g2 = g[(size_t)n * GHID + 64 + lane];
#pragma unroll
    for (int e = 0; e < NEXP; ++e)
        p[e] = g1 * Wg2[lane * NEXP + e] + g2 * Wg2[(64 + lane) * NEXP + e];
#pragma unroll
    for (int off = 32; off > 0; off >>= 1)
#pragma unroll
        for (int e = 0; e < NEXP; ++e) p[e] += __shfl_xor(p[e], off, 64);
    if (lane == 0) {
        float l[NEXP], mx = -1e30f;
#pragma unroll
        for (int e = 0; e < NEXP; ++e) { l[e] = p[e] + bg2[e]; mx = fmaxf(mx, l[e]); }
        float pr[NEXP], s = 0.f;
#pragma unroll
        for (int e = 0; e < NEXP; ++e) { pr[e] = expf(l[e] - mx); s += pr[e]; }
#pragma unroll
        for (int e = 0; e < NEXP; ++e) pr[e] /= s;
        int i0 = 0;
#pragma unroll
        for (int e = 1; e < NEXP; ++e) if (pr[e] > pr[i0]) i0 = e;
        int i1 = -1;
#pragma unroll
        for (int e = 0; e < NEXP; ++e) if (e != i0 && (i1 < 0 || pr[e] > pr[i1])) i1 = e;
        float v0 = pr[i0], v1 = pr[i1], s2 = v0 + v1;
        gates[2 * n]     = v0 / s2;
        gates[2 * n + 1] = v1 / s2;
        esel[2 * n]      = i0;
        esel[2 * n + 1]  = i1;
    }
}

// ---------- slot machinery: per-(expert,rank) 128-padded compaction ----------
__global__ __launch_bounds__(256) void slot_count(const int* __restrict__ esel,
                                                  int* __restrict__ slotcnt) {
    __shared__ int h[10];
    if (threadIdx.x < 10) h[threadIdx.x] = 0;
    __syncthreads();
    int n = blockIdx.x * 256 + threadIdx.x;
    if (n < NNODE) {
        atomicAdd(&h[esel[2 * n] * 2 + 0], 1);
        atomicAdd(&h[esel[2 * n + 1] * 2 + 1], 1);
    }
    __syncthreads();
    if (threadIdx.x < 10) atomicAdd(&slotcnt[threadIdx.x], h[threadIdx.x]);
}
// header: [0]=tiles_all, [1]=tiles_rank0, [2]=tiles_rank1
__global__ void seg_plan(const int* __restrict__ slotcnt, int* __restrict__ cursor,
                         int* __restrict__ header, int2* __restrict__ meta_all,
                         int2* __restrict__ meta_r0, int2* __restrict__ meta_r1) {
    if (threadIdx.x == 0 && blockIdx.x == 0) {
        int base = 0, ta = 0, t0 = 0, t1 = 0;
        for (int s = 0; s < 10; ++s) {
            cursor[s] = base;
            int nt = (slotcnt[s] + 127) >> 7;
            for (int k = 0; k < nt; ++k) {
                int2 m; m.x = s; m.y = base + k * 128;
                meta_all[ta++] = m;
                if (s & 1) meta_r1[t1++] = m; else meta_r0[t0++] = m;
            }
            base += nt * 128;
        }
        header[0] = ta; header[1] = t0; header[2] = t1;
    }
}
__global__ __launch_bounds__(256) void slot_fill(
    const int* __restrict__ esel, const float* __restrict__ gates, int* __restrict__ cursor,
    int* __restrict__ rowlist, float* __restrict__ gateval) {
    __shared__ int h[10], base[10];
    if (threadIdx.x < 10) h[threadIdx.x] = 0;
    __syncthreads();
    int n = blockIdx.x * 256 + threadIdx.x;
    int s0 = 0, s1 = 0, p0 = 0, p1 = 0;
    bool on = (n < NNODE);
    if (on) {
        s0 = esel[2 * n] * 2;
        s1 = esel[2 * n + 1] * 2 + 1;
        p0 = atomicAdd(&h[s0], 1);
        p1 = atomicAdd(&h[s1], 1);
    }
    __syncthreads();
    if (threadIdx.x < 10) base[threadIdx.x] = atomicAdd(&cursor[threadIdx.x], h[threadIdx.x]);
    __syncthreads();
    if (on) {
        int q0 = base[s0] + p0, q1 = base[s1] + p1;
        rowlist[q0] = n; gateval[q0] = gates[2 * n];
        rowlist[q1] = n; gateval[q1] = gates[2 * n + 1];
    }
}

// ---------- expert layer 1 (compacted): h1[slot] = gelu(x[rowlist[slot]] @ We1[e] + be1[e]) ----------
// 1-D grid, XCD-affinity remap: the 4 N-tiles sharing an A-panel land on one XCD.
__global__ __launch_bounds__(256) void gemm_moe1(
    const float* __restrict__ xtab, const float* __restrict__ xstr, const float* __restrict__ xtxt,
    const unsigned short* __restrict__ We1t, const float* __restrict__ be1,
    const int* __restrict__ header, const int2* __restrict__ meta,
    const int* __restrict__ rowlist, unsigned short* __restrict__ h1) {
    const int wg = blockIdx.x;
    const int xcd = wg & 7, s = wg >> 3;
    const int mt_i = (s >> 2) * 8 + xcd;    // tile index (A-panel)
    const int ntile = s & 3;                // N-tile
    if (mt_i >= header[0]) return;
    __shared__ unsigned short As[128 * 64];
    __shared__ unsigned short Bs[128 * 64];
    int2 mt = meta[mt_i];
    const int eid = mt.x >> 1, rowbase = mt.y;
    const float* xf = (eid == 0) ? xtab : ((eid == 1 || eid == 4) ? xstr : xtxt);
    const int t = threadIdx.x, w = t >> 6, lane = t & 63;
    const int ln = lane & 15, q = lane >> 4;
    const int wm = (w >> 1) * 64, wn = (w & 1) * 64;
    const int rb = w * 8 + (lane >> 3), kg = lane & 7;
    const int koff = (kg ^ (rb & 7)) * 8;
    int rows[4];
#pragma unroll
    for (int it = 0; it < 4; ++it) {
        int rr = rowlist[rowbase + rb + 32 * it];
        rows[it] = (rr < 0) ? 0 : rr;
    }
    const unsigned short* Bg = We1t + (size_t)eid * HDIM * EDIM
                             + (size_t)(ntile * 128 + rb) * EDIM + koff;
    unsigned short* Bl = &Bs[rb * 64 + kg * 8];
    float4v acc[4][4];
#pragma unroll
    for (int i = 0; i < 4; ++i)
#pragma unroll
        for (int j = 0; j < 4; ++j) acc[i][j] = (float4v){0.f, 0.f, 0.f, 0.f};

    for (int kt = 0; kt < EDIM; kt += 64) {
        __syncthreads();
#pragma unroll
        for (int it = 0; it < 4; ++it) {
            const float* sp = xf + (size_t)rows[it] * EDIM + kt + koff;
            float4v a0 = *(const float4v*)sp;
            float4v a1 = *(const float4v*)(sp + 4);
            union { short8 v; unsigned short s[8]; } pk;
#pragma unroll
            for (int c = 0; c < 4; ++c) { pk.s[c] = f2b(a0[c]); pk.s[4 + c] = f2b(a1[c]); }
            *(short8*)&As[(rb + 32 * it) * 64 + kg * 8] = pk.v;
            gl_lds16(Bg + (size_t)it * 32 * EDIM + kt, Bl + it * 32 * 64);
        }
        __syncthreads();
#pragma unroll
        for (int kk = 0; kk < 2; ++kk) {
            short8 af[4], bf[4];
#pragma unroll
            for (int i = 0; i < 4; ++i)
                af[i] = *(const short8*)&As[(wm + 16 * i + ln) * 64 + (((kk * 4 + q) ^ (ln & 7)) * 8)];
#pragma unroll
            for (int j = 0; j < 4; ++j)
                bf[j] = *(const short8*)&Bs[(wn + 16 * j + ln) * 64 + (((kk * 4 + q) ^ (ln & 7)) * 8)];
#pragma unroll
            for (int i = 0; i < 4; ++i)
#pragma unroll
                for (int j = 0; j < 4; ++j)
                    acc[i][j] = __builtin_amdgcn_mfma_f32_16x16x32_bf16(af[i], bf[j], acc[i][j], 0, 0, 0);
        }
    }
    const int gn0 = ntile * 128 + wn;
#pragma unroll
    for (int i = 0; i < 4; ++i)
#pragma unroll
        for (int j = 0; j < 4; ++j) {
            int gn = gn0 + 16 * j + ln;
            float bc = be1[eid * HDIM + gn];
#pragma unroll
            for (int r = 0; r < 4; ++r) {
                int slot = rowbase + wm + 16 * i + q * 4 + r;
                h1[(size_t)slot * HDIM + gn] = f2b(gelu_tanh(acc[i][j][r] + bc));
            }
        }
}

// ---------- expert layer 2 (compacted, scatter): nf[node] (+)= gate*(h1[slot]@We2[e] + be2[e]) ----------
template<int RMW>
__global__ __launch_bounds__(256) void gemm_moe2(
    const unsigned short* __restrict__ h1, const unsigned short* __restrict__ We2t,
    const float* __restrict__ be2, const int* __restrict__ header,
    const int2* __restrict__ meta, const int* __restrict__ rowlist,
    const float* __restrict__ gateval, unsigned short* __restrict__ nf) {
    const int wg = blockIdx.x;
    const int xcd = wg & 7, s = wg >> 3;
    const int mt_i = (s >> 2) * 8 + xcd;
    const int ntile = s & 3;
    if (mt_i >= header[RMW ? 2 : 1]) return;
    __shared__ unsigned short As[128 * 64];
    __shared__ unsigned short Bs[128 * 64];
    int2 mt = meta[mt_i];
    const int eid = mt.x >> 1, rowbase = mt.y;
    const int t = threadIdx.x, w = t >> 6, lane = t & 63;
    const int ln = lane & 15, q = lane >> 4;
    const int wm = (w >> 1) * 64, wn = (w & 1) * 64;
    const int rb = w * 8 + (lane >> 3), kg = lane & 7;
    const int koff = (kg ^ (rb & 7)) * 8;
    const unsigned short* Ag = h1 + (size_t)(rowbase + rb) * HDIM + koff;
    const unsigned short* Bg = We2t + (size_t)eid * HDIM * HDIM
                             + (size_t)(ntile * 128 + rb) * HDIM + koff;
    unsigned short* Al = &As[rb * 64 + kg * 8];
    unsigned short* Bl = &Bs[rb * 64 + kg * 8];
    float4v acc[4][4];
#pragma unroll
    for (int i = 0; i < 4; ++i)
#pragma unroll
        for (int j = 0; j < 4; ++j) acc[i][j] = (float4v){0.f, 0.f, 0.f, 0.f};

    for (int kt = 0; kt < HDIM; kt += 64) {
        __syncthreads();
#pragma unroll
        for (int it = 0; it < 4; ++it) {
            gl_lds16(Ag + (size_t)it * 32 * HDIM + kt, Al + it * 32 * 64);
            gl_lds16(Bg + (size_t)it * 32 * HDIM + kt, Bl + it * 32 * 64);
        }
        __syncthreads();
#pragma unroll
        for (int kk = 0; kk < 2; ++kk) {
            short8 af[4], bf[4];
#pragma unroll
            for (int i = 0; i < 4; ++i)
                af[i] = *(const short8*)&As[(wm + 16 * i + ln) * 64 + (((kk * 4 + q) ^ (ln & 7)) * 8)];
#pragma unroll
            for (int j = 0; j < 4; ++j)
                bf[j] = *(const short8*)&Bs[(wn + 16 * j + ln) * 64 + (((kk * 4 + q) ^ (ln & 7)) * 8)];
#pragma unroll
            for (int i = 0; i < 4; ++i)
#pragma unroll
                for (int j = 0; j < 4; ++j)
                    acc[i][j] = __builtin_amdgcn_mfma_f32_16x16x32_bf16(af[i], bf[j], acc[i][j], 0, 0, 0);
        }
    }
    const int gn0 = ntile * 128 + wn;
#pragma unroll
    for (int i = 0; i < 4; ++i)
#pragma unroll
        for (int r = 0; r < 4; ++r) {
            int slot = rowbase + wm + 16 * i + q * 4 + r;
            int node = rowlist[slot];
            if (node >= 0) {
                float gt = gateval[slot];
#pragma unroll
                for (int j = 0; j < 4; ++j) {
                    int gn = gn0 + 16 * j + ln;
                    size_t o = (size_t)node * HDIM + gn;
                    float v = gt * (acc[i][j][r] + be2[eid * HDIM + gn]);
                    nf[o] = RMW ? f2b(b2f(nf[o]) + v) : f2b(v);
                }
            }
        }
}

// ---------- GNN fused layer: C = relu([h, agg] @ [Wself; Wnbr])  (K=1024 concat) ----------
#define GNN_MT (M_PAD / 128)   // 391
template<int FINAL>
__global__ __launch_bounds__(256) void gemm_gnn(
    const unsigned short* __restrict__ A0, const unsigned short* __restrict__ A1,
    const unsigned short* __restrict__ Bt, unsigned short* __restrict__ Cb,
    float* __restrict__ Cf) {
    const int wg = blockIdx.x;
    const int xcd = wg & 7, s = wg >> 3;
    const int mt = (s >> 2) * 8 + xcd;      // M-tile
    const int ntile = s & 3;                // N-tile
    if (mt >= GNN_MT) return;
    __shared__ unsigned short As[128 * 64];
    __shared__ unsigned short Bs[128 * 64];
    const int t = threadIdx.x, w = t >> 6, lane = t & 63;
    const int ln = lane & 15, q = lane >> 4;
    const int wm = (w >> 1) * 64, wn = (w & 1) * 64;
    const int rb = w * 8 + (lane >> 3), kg = lane & 7;
    const int koff = (kg ^ (rb & 7)) * 8;
    const unsigned short* Ag0 = A0 + (size_t)(mt * 128 + rb) * HDIM + koff;
    const unsigned short* Ag1 = A1 + (size_t)(mt * 128 + rb) * HDIM + koff;
    const unsigned short* Bg  = Bt + (size_t)(ntile * 128 + rb) * 1024 + koff;
    unsigned short* Al = &As[rb * 64 + kg * 8];
    unsigned short* Bl = &Bs[rb * 64 + kg * 8];
    float4v acc[4][4];
#pragma unroll
    for (int i = 0; i < 4; ++i)
#pragma unroll
        for (int j = 0; j < 4; ++j) acc[i][j] = (float4v){0.f, 0.f, 0.f, 0.f};

    for (int kt = 0; kt < 1024; kt += 64) {
        __syncthreads();
#pragma unroll
        for (int it = 0; it < 4; ++it) {
            const unsigned short* asrc = (kt < HDIM)
                ? (Ag0 + (size_t)it * 32 * HDIM + kt)
                : (Ag1 + (size_t)it * 32 * HDIM + (kt - HDIM));
            gl_lds16(asrc, Al + it * 32 * 64);
            gl_lds16(Bg + (size_t)it * 32 * 1024 + kt, Bl + it * 32 * 64);
        }
        __syncthreads();
#pragma unroll
        for (int kk = 0; kk < 2; ++kk) {
            short8 af[4], bf[4];
#pragma unroll
            for (int i = 0; i < 4; ++i)
                af[i] = *(const short8*)&As[(wm + 16 * i + ln) * 64 + (((kk * 4 + q) ^ (ln & 7)) * 8)];
#pragma unroll
            for (int j = 0; j < 4; ++j)
                bf[j] = *(const short8*)&Bs[(wn + 16 * j + ln) * 64 + (((kk * 4 + q) ^ (ln & 7)) * 8)];
#pragma unroll
            for (int i = 0; i < 4; ++i)
#pragma unroll
                for (int j = 0; j < 4; ++j)
                    acc[i][j] = __builtin_amdgcn_mfma_f32_16x16x32_bf16(af[i], bf[j], acc[i][j], 0, 0, 0);
        }
    }
    const int gm0 = mt * 128 + wm;
    const int gn0 = ntile * 128 + wn;
#pragma unroll
    for (int i = 0; i < 4; ++i)
#pragma unroll
        for (int j = 0; j < 4; ++j) {
            int gn = gn0 + 16 * j + ln;
#pragma unroll
            for (int r = 0; r < 4; ++r) {
                int gm = gm0 + 16 * i + q * 4 + r;
                float v = fmaxf(acc[i][j][r], 0.f);
                if (FINAL) {
                    if (gm < NNODE) Cf[(size_t)gm * HDIM + gn] = v;
                } else {
                    Cb[(size_t)gm * HDIM + gn] = f2b(v);
                }
            }
        }
}

// ---------- CSR build ----------
__global__ void hist_kernel(const int* __restrict__ dst, int* __restrict__ deg) {
    int i = blockIdx.x * blockDim.x + threadIdx.x;
    if (i < NEDGE) atomicAdd(&deg[dst[i]], 1);
}
__global__ void scan_block(const int* __restrict__ in, int* __restrict__ incl,
                           int* __restrict__ bsum, int n) {
    __shared__ int s[256];
    int i = blockIdx.x * 256 + threadIdx.x;
    s[threadIdx.x] = (i < n) ? in[i] : 0;
    __syncthreads();
    for (int off = 1; off < 256; off <<= 1) {
        int t = (threadIdx.x >= (unsigned)off) ? s[threadIdx.x - off] : 0;
        __syncthreads();
        s[threadIdx.x] += t;
        __syncthreads();
    }
    if (i < n) incl[i] = s[threadIdx.x];
    if (bsum != nullptr && threadIdx.x == 255) bsum[blockIdx.x] = s[255];
}
__global__ void scan_fix(const int* __restrict__ incl, const int* __restrict__ deg,
                         const int* __restrict__ bscan, int* __restrict__ rowstart,
                         int* __restrict__ ecur) {
    int i = blockIdx.x * blockDim.x + threadIdx.x;
    if (i < NNODE) {
        int b = i >> 8;
        int add = (b > 0) ? bscan[b - 1] : 0;
        int st = incl[i] - deg[i] + add;
        rowstart[i] = st;
        ecur[i] = st;
    }
}
__global__ void fill_csr(const int* __restrict__ src, const int* __restrict__ dst,
                         int* __restrict__ ecur, int* __restrict__ srcs) {
    int e = blockIdx.x * blockDim.x + threadIdx.x;
    if (e < NEDGE) {
        int pos = atomicAdd(&ecur[dst[e]], 1);
        srcs[pos] = src[e];
    }
}

// ---------- segment-sum of bf16 rows -> bf16: agg[n] = sum_{s in nbrs(n)} h[s] ----------
// One wave per node (4 nodes/block). No LDS, no barriers. Round-1 proven version:
// at the fabric ceiling (~3.6 TB/s L2-miss path) for this random 1KB-row gather.
__global__ __launch_bounds__(256) void msg_sum_w(
    const unsigned short* __restrict__ h, const int* __restrict__ rowstart,
    const int* __restrict__ deg, const int* __restrict__ srcs,
    unsigned short* __restrict__ agg) {
    const int wv = threadIdx.x >> 6, lane = threadIdx.x & 63;
    const int n = blockIdx.x * 4 + wv;
    const int st = rowstart[n], d = deg[n];
    float acc[8] = {0.f,0.f,0.f,0.f,0.f,0.f,0.f,0.f};
    const unsigned short* hp = h + (size_t)lane * 8;
    for (int cb = 0; cb < d; cb += 64) {
        int cnt = d - cb; if (cnt > 64) cnt = 64;
        int sidx = (cb + lane < d) ? srcs[st + cb + lane] : 0;
        int t = 0;
        for (; t + 4 <= cnt; t += 4) {
            int s0 = __shfl(sidx, t,     64);
            int s1 = __shfl(sidx, t + 1, 64);
            int s2 = __shfl(sidx, t + 2, 64);
            int s3 = __shfl(sidx, t + 3, 64);
            short8 v0 = *(const short8*)(hp + (size_t)s0 * HDIM);
            short8 v1 = *(const short8*)(hp + (size_t)s1 * HDIM);
            short8 v2 = *(const short8*)(hp + (size_t)s2 * HDIM);
            short8 v3 = *(const short8*)(hp + (size_t)s3 * HDIM);
#pragma unroll
            for (int c = 0; c < 8; ++c)
                acc[c] += (b2f((unsigned short)v0[c]) + b2f((unsigned short)v1[c]))
                        + (b2f((unsigned short)v2[c]) + b2f((unsigned short)v3[c]));
        }
        for (; t < cnt; ++t) {
            int s = __shfl(sidx, t, 64);
            short8 v = *(const short8*)(hp + (size_t)s * HDIM);
#pragma unroll
            for (int c = 0; c < 8; ++c) acc[c] += b2f((unsigned short)v[c]);
        }
    }
    union { short8 v; unsigned short s[8]; } o;
#pragma unroll
    for (int c = 0; c < 8; ++c) o.s[c] = f2b(acc[c]);
    *(short8*)(agg + (size_t)n * HDIM + lane * 8) = o.v;
}

extern "C" void kernel_launch(void* const* d_in, const int* in_sizes, int n_in,
                              void* d_out, int out_size, void* d_ws, size_t ws_size,
                              hipStream_t stream) {
    (void)in_sizes; (void)n_in; (void)out_size; (void)ws_size;
    const float* text       = (const float*)d_in[0];
    const float* tabular    = (const float*)d_in[1];
    const float* structured = (const float*)d_in[2];
    const int*   e_in       = (const int*)d_in[3];
    const float* Wg1  = (const float*)d_in[4];
    const float* bg1  = (const float*)d_in[5];
    const float* Wg2  = (const float*)d_in[6];
    const float* bg2  = (const float*)d_in[7];
    const float* We1  = (const float*)d_in[8];
    const float* be1  = (const float*)d_in[9];
    const float* We2  = (const float*)d_in[10];
    const float* be2  = (const float*)d_in[11];
    const float* Wself = (const float*)d_in[12];
    const float* Wnbr  = (const float*)d_in[13];
    const int* src = e_in;
    const int* dst = e_in + NEDGE;
    float* dout = (float*)d_out;

    // ---- workspace carve-up (regions overlap across phases; ~220 MB total) ----
    char* w = (char*)d_ws;
    auto alloc = [&](size_t bytes) { char* p = w; w += (bytes + 511) & ~(size_t)511; return p; };
    const size_t SZ_H = (size_t)M_PAD * HDIM * 2;            // 51.25 MB
    unsigned short* We1t  = (unsigned short*)alloc((size_t)NEXP * HDIM * EDIM * 2);
    unsigned short* We2t  = (unsigned short*)alloc((size_t)NEXP * HDIM * HDIM * 2);
    unsigned short* Wcat0 = (unsigned short*)alloc((size_t)HDIM * 1024 * 2);
    unsigned short* Wcat1 = (unsigned short*)alloc((size_t)HDIM * 1024 * 2);
    unsigned short* Wg1h  = (unsigned short*)alloc((size_t)GHID * 768 * 2);
    unsigned short* Wg1l  = (unsigned short*)alloc((size_t)GHID * 768 * 2);
    float* gates    = (float*)alloc((size_t)NNODE * 2 * 4);
    int*   esel     = (int*)alloc((size_t)NNODE * 2 * 4);
    int*   slotcnt  = (int*)alloc(16 * 4);
    int*   scursor  = (int*)alloc(16 * 4);
    int*   header   = (int*)alloc(16 * 4);
    int2*  meta_all = (int2*)alloc((size_t)MAXT_ALL * 8);
    int2*  meta_r0  = (int2*)alloc((size_t)MAXT_R * 8);
    int2*  meta_r1  = (int2*)alloc((size_t)MAXT_R * 8);
    int*   rowlist  = (int*)alloc((size_t)SLOTCAP * 4);
    float* gateval  = (float*)alloc((size_t)SLOTCAP * 4);
    int*   deg      = (int*)alloc((size_t)NNODE * 4);
    int*   incl     = (int*)alloc((size_t)NNODE * 4);
    int*   bsum     = (int*)alloc(1024 * 4);
    int*   bscan    = (int*)alloc(1024 * 4);
    int*   rowstart = (int*)alloc((size_t)NNODE * 4);
    int*   ecur     = (int*)alloc((size_t)NNODE * 4);
    int*   srcs     = (int*)alloc((size_t)NEDGE * 4);
    unsigned short* nfb = (unsigned short*)alloc(SZ_H);
    // region A: gbuf (gate hidden, fp32) dead after gating; aggb alive only in GNN
    char* regA = alloc((size_t)M_PAD * GHID * 4 > SZ_H ? (size_t)M_PAD * GHID * 4 : SZ_H);
    float*          gbuf = (float*)regA;
    unsigned short* aggb = (unsigned short*)regA;
    // region B: h1c (compacted expert hidden) dead after moe2; hb alive only in GNN
    char* regB = alloc((size_t)SLOTCAP * HDIM * 2);
    unsigned short* h1c = (unsigned short*)regB;
    unsigned short* hb  = (unsigned short*)regB;

    // ---- weight prep + workspace init: single fused kernel, no memsets ----
    wprep<<<1024, 256, 0, stream>>>(We1, We2, Wself, Wnbr, Wg1,
                                    We1t, We2t, Wcat0, Wcat1, Wg1h, Wg1l,
                                    rowlist, deg, slotcnt);

    // ---- gate (bf16x3 split, fp32 fidelity) + routing ----
    gate128<<<dim3(1, M_PAD / 128), 256, 0, stream>>>(text, tabular, structured,
                                                      Wg1h, Wg1l, bg1, gbuf);
    gating<<<NNODE / 4, 256, 0, stream>>>(gbuf, Wg2, bg2, gates, esel);

    // ---- compaction plan ----
    slot_count<<<(NNODE + 255) / 256, 256, 0, stream>>>(esel, slotcnt);
    seg_plan<<<1, 64, 0, stream>>>(slotcnt, scursor, header, meta_all, meta_r0, meta_r1);
    slot_fill<<<(NNODE + 255) / 256, 256, 0, stream>>>(esel, gates, scursor, rowlist, gateval);

    // ---- experts on routed rows only (XCD-affinity 1-D grids) ----
    gemm_moe1<<<MAXT_ALL * 4, 256, 0, stream>>>(
        tabular, structured, text, We1t, be1, header, meta_all, rowlist, h1c);
    gemm_moe2<0><<<8 * 50 * 4, 256, 0, stream>>>(
        h1c, We2t, be2, header, meta_r0, rowlist, gateval, nfb);
    gemm_moe2<1><<<8 * 50 * 4, 256, 0, stream>>>(
        h1c, We2t, be2, header, meta_r1, rowlist, gateval, nfb);

    // ---- CSR of edges grouped by dst ----
    const int NB = (NNODE + 255) / 256;
    hist_kernel<<<(NEDGE + 255) / 256, 256, 0, stream>>>(dst, deg);
    scan_block<<<NB, 256, 0, stream>>>(deg, incl, bsum, NNODE);
    scan_block<<<1, 256, 0, stream>>>(bsum, bscan, nullptr, NB);
    scan_fix<<<NB, 256, 0, stream>>>(incl, deg, bscan, rowstart, ecur);
    fill_csr<<<(NEDGE + 255) / 256, 256, 0, stream>>>(src, dst, ecur, srcs);

    // ---- GNN layer 0: agg = segsum(nf); h = relu([nf,agg] @ Wcat0) ----
    msg_sum_w<<<NNODE / 4, 256, 0, stream>>>(nfb, rowstart, deg, srcs, aggb);
    gemm_gnn<0><<<8 * 49 * 4, 256, 0, stream>>>(nfb, aggb, Wcat0, hb, nullptr);

    // ---- GNN layer 1: agg = segsum(h); out = relu([h,agg] @ Wcat1) ----
    msg_sum_w<<<NNODE / 4, 256, 0, stream>>>(hb, rowstart, deg, srcs, aggb);
    gemm_gnn<1><<<8 * 49 * 4, 256, 0, stream>>>(hb, aggb, Wcat1, nullptr, dout);
}